// Round 8
// baseline (4509.576 us; speedup 1.0000x reference)
//
#include <hip/hip_runtime.h>
#include <math.h>

#define B_ 8
#define S_ 2048
#define E_ 1024
#define H_ 1024
#define M_ 16384   // B_*S_

typedef __attribute__((ext_vector_type(8))) short short8;    // 8 bf16 = 4 VGPRs
typedef __attribute__((ext_vector_type(4))) float floatx4;

// ---------------- block-wide reduction of two floats (256 threads = 4 waves) ----------------
__device__ __forceinline__ void block_reduce2(float &a, float &b) {
#pragma unroll
  for (int off = 32; off > 0; off >>= 1) {
    a += __shfl_down(a, off);
    b += __shfl_down(b, off);
  }
  __shared__ float sa[4], sb[4];
  const int w = threadIdx.x >> 6;
  __syncthreads();                 // protects reuse across back-to-back calls
  if ((threadIdx.x & 63) == 0) { sa[w] = a; sb[w] = b; }
  __syncthreads();
  a = sa[0] + sa[1] + sa[2] + sa[3];
  b = sb[0] + sb[1] + sb[2] + sb[3];
}

__device__ __forceinline__ unsigned pack_bf16(float lo, float hi) {
  return __builtin_amdgcn_perm(__float_as_uint(hi) + 0x8000u,
                               __float_as_uint(lo) + 0x8000u, 0x07060302u);
}
// pack the hi16 of two u32 bit patterns: (hi16(a) in low half, hi16(b) in high half)
__device__ __forceinline__ unsigned pack_hi16(unsigned a, unsigned b) {
  return __builtin_amdgcn_perm(b, a, 0x07060302u);
}

// ---------------- LayerNorm(x) -> x_norm (bf16!), plus delta = softplus(x_norm . delta_w + db) ----------------
__global__ __launch_bounds__(256) void ln_delta_kernel(
    const float* __restrict__ x, const float* __restrict__ g, const float* __restrict__ bt,
    const float* __restrict__ dw, const float* __restrict__ db,
    unsigned short* __restrict__ xnb, float* __restrict__ delta)
{
  const int row = blockIdx.x;
  const int t = threadIdx.x;
  const float4 v = ((const float4*)(x + (size_t)row * E_))[t];
  float s1 = v.x + v.y + v.z + v.w;
  float s2 = v.x*v.x + v.y*v.y + v.z*v.z + v.w*v.w;
  block_reduce2(s1, s2);
  const float mean = s1 * (1.f / E_);
  const float var  = s2 * (1.f / E_) - mean * mean;
  const float rstd = rsqrtf(var + 1e-5f);
  const float4 g4 = ((const float4*)g)[t];
  const float4 b4 = ((const float4*)bt)[t];
  float4 o;
  o.x = (v.x - mean) * rstd * g4.x + b4.x;
  o.y = (v.y - mean) * rstd * g4.y + b4.y;
  o.z = (v.z - mean) * rstd * g4.z + b4.z;
  o.w = (v.w - mean) * rstd * g4.w + b4.w;
  uint2 p;
  p.x = pack_bf16(o.x, o.y); p.y = pack_bf16(o.z, o.w);
  ((uint2*)(xnb + (size_t)row * E_))[t] = p;       // bf16 x_norm (same rounding the GEMMs used)
  const float4 d4 = ((const float4*)dw)[t];
  float dd = o.x*d4.x + o.y*d4.y + o.z*d4.z + o.w*d4.w;   // delta stays fp32-accurate
  float dummy = 0.f;
  block_reduce2(dd, dummy);
  if (t == 0) {
    const float z = dd + db[0];
    delta[row] = (z > 20.f) ? z : log1pf(__expf(z));
  }
}

// ---------------- per-row mean/rstd of reservoir states (for fused ro-layernorm) ----------------
__global__ __launch_bounds__(256) void rowstats_kernel(
    const float* __restrict__ res, float2* __restrict__ st)
{
  const int row = blockIdx.x;
  const int t = threadIdx.x;
  const float4 v = ((const float4*)(res + (size_t)row * H_))[t];
  float s1 = v.x + v.y + v.z + v.w;
  float s2 = v.x*v.x + v.y*v.y + v.z*v.z + v.w*v.w;
  block_reduce2(s1, s2);
  if (t == 0) {
    const float m = s1 * (1.f / H_);
    const float var = s2 * (1.f / H_) - m * m;
    st[row] = make_float2(m, rsqrtf(var + 1e-5f));
  }
}

// ---------------- tiny converters (run once, off critical path) ----------------
__global__ __launch_bounds__(256) void tobf16_kernel(
    const float* __restrict__ s, unsigned short* __restrict__ d)
{
  const int i = blockIdx.x * 256 + threadIdx.x;
  const float4 v = ((const float4*)s)[i];
  uint2 p;
  p.x = pack_bf16(v.x, v.y); p.y = pack_bf16(v.z, v.w);
  ((uint2*)d)[i] = p;
}

__global__ __launch_bounds__(256) void splitw_kernel(
    const float* __restrict__ s, unsigned short* __restrict__ dh, unsigned short* __restrict__ dl)
{
  const int i = blockIdx.x * 256 + threadIdx.x;
  const float4 v = ((const float4*)s)[i];
  const float sv[4] = {v.x, v.y, v.z, v.w};
  unsigned h[4]; float l[4];
#pragma unroll
  for (int e = 0; e < 4; ++e) {
    h[e] = (__float_as_uint(sv[e]) + 0x8000u) & 0xFFFF0000u;
    l[e] = sv[e] - __uint_as_float(h[e]);
  }
  uint2 ph, pl;
  ph.x = pack_hi16(h[0], h[1]); ph.y = pack_hi16(h[2], h[3]);
  pl.x = pack_bf16(l[0], l[1]); pl.y = pack_bf16(l[2], l[3]);
  ((uint2*)dh)[i] = ph;
  ((uint2*)dl)[i] = pl;
}

// ---------------- bf16-input MFMA GEMM: C[M,N] = A[M,1024] @ W[N,1024]^T (A,W bf16) ----------------
__global__ __launch_bounds__(256) void gemm_bb(
    const unsigned short* __restrict__ A, const unsigned short* __restrict__ W,
    float* __restrict__ C)
{
  __shared__ __align__(16) unsigned short As[128 * 40];
  __shared__ __align__(16) unsigned short Ws[128 * 40];
  const int tid  = threadIdx.x;
  const int bn   = blockIdx.x & 7;
  const int bm   = blockIdx.x >> 3;
  const int wave = tid >> 6, lane = tid & 63;
  const int wm = (wave >> 1) * 64, wn = (wave & 1) * 64;
  const int fm = lane & 15, quad = lane >> 4;

  floatx4 acc[4][4];
#pragma unroll
  for (int i = 0; i < 4; ++i)
#pragma unroll
    for (int j = 0; j < 4; ++j) acc[i][j] = (floatx4){0.f, 0.f, 0.f, 0.f};

  const unsigned short* Abase = A + (size_t)bm * 128 * 1024;
  const unsigned short* Wbase = W + (size_t)bn * 128 * 1024;

  for (int k0 = 0; k0 < 1024; k0 += 32) {
    uint2 a2[4], w2[4];
#pragma unroll
    for (int i = 0; i < 4; ++i) {
      const int q = tid + 256 * i;
      const int row = q >> 3, ch = q & 7;
      a2[i] = *(const uint2*)(Abase + (size_t)row * 1024 + k0 + ch * 4);
      w2[i] = *(const uint2*)(Wbase + (size_t)row * 1024 + k0 + ch * 4);
    }
#pragma unroll
    for (int i = 0; i < 4; ++i) {
      const int q = tid + 256 * i;
      const int row = q >> 3, ch = q & 7;
      *(uint2*)(&As[row * 40 + ch * 4]) = a2[i];
      *(uint2*)(&Ws[row * 40 + ch * 4]) = w2[i];
    }
    __syncthreads();
    short8 af[4], wf[4];
#pragma unroll
    for (int i = 0; i < 4; ++i) {
      af[i] = *(const short8*)(&As[(wm + i * 16 + fm) * 40 + quad * 8]);
      wf[i] = *(const short8*)(&Ws[(wn + i * 16 + fm) * 40 + quad * 8]);
    }
#pragma unroll
    for (int i = 0; i < 4; ++i)
#pragma unroll
      for (int j = 0; j < 4; ++j)
        acc[i][j] = __builtin_amdgcn_mfma_f32_16x16x32_bf16(af[i], wf[j], acc[i][j], 0, 0, 0);
    __syncthreads();
  }

  // epilogue: C/D layout col=lane&15, row=quad*4+reg (m89/m91)
#pragma unroll
  for (int i = 0; i < 4; ++i) {
    const int grow0 = bm * 128 + wm + i * 16 + quad * 4;
#pragma unroll
    for (int j = 0; j < 4; ++j) {
      const int gcol = bn * 128 + wn + j * 16 + fm;
#pragma unroll
      for (int r = 0; r < 4; ++r)
        C[(size_t)(grow0 + r) * 1024 + gcol] = acc[i][j][r];
    }
  }
}

// ---------------- fp32-input bf16 MFMA GEMM with sigmoid (gate) ----------------
template<int ACT>
__global__ __launch_bounds__(256) void gemm_bf16_nt(
    const float* __restrict__ A, const float* __restrict__ W,
    const float* __restrict__ bias, float* __restrict__ C)
{
  __shared__ __align__(16) unsigned short As[128 * 40];
  __shared__ __align__(16) unsigned short Ws[128 * 40];
  const int tid  = threadIdx.x;
  const int bn   = blockIdx.x & 7;
  const int bm   = blockIdx.x >> 3;
  const int wave = tid >> 6, lane = tid & 63;
  const int wm = (wave >> 1) * 64, wn = (wave & 1) * 64;
  const int fm = lane & 15, quad = lane >> 4;

  floatx4 acc[4][4];
#pragma unroll
  for (int i = 0; i < 4; ++i)
#pragma unroll
    for (int j = 0; j < 4; ++j) acc[i][j] = (floatx4){0.f, 0.f, 0.f, 0.f};

  const float* Abase = A + (size_t)bm * 128 * 1024;
  const float* Wbase = W + (size_t)bn * 128 * 1024;

  for (int k0 = 0; k0 < 1024; k0 += 32) {
    float4 a4[4], w4[4];
#pragma unroll
    for (int i = 0; i < 4; ++i) {
      const int q = tid + 256 * i;
      const int row = q >> 3, ch = q & 7;
      a4[i] = *(const float4*)(Abase + (size_t)row * 1024 + k0 + ch * 4);
      w4[i] = *(const float4*)(Wbase + (size_t)row * 1024 + k0 + ch * 4);
    }
#pragma unroll
    for (int i = 0; i < 4; ++i) {
      const int q = tid + 256 * i;
      const int row = q >> 3, ch = q & 7;
      uint2 pa, pw;
      pa.x = pack_bf16(a4[i].x, a4[i].y); pa.y = pack_bf16(a4[i].z, a4[i].w);
      pw.x = pack_bf16(w4[i].x, w4[i].y); pw.y = pack_bf16(w4[i].z, w4[i].w);
      *(uint2*)(&As[row * 40 + ch * 4]) = pa;
      *(uint2*)(&Ws[row * 40 + ch * 4]) = pw;
    }
    __syncthreads();
    short8 af[4], wf[4];
#pragma unroll
    for (int i = 0; i < 4; ++i) {
      af[i] = *(const short8*)(&As[(wm + i * 16 + fm) * 40 + quad * 8]);
      wf[i] = *(const short8*)(&Ws[(wn + i * 16 + fm) * 40 + quad * 8]);
    }
#pragma unroll
    for (int i = 0; i < 4; ++i)
#pragma unroll
      for (int j = 0; j < 4; ++j)
        acc[i][j] = __builtin_amdgcn_mfma_f32_16x16x32_bf16(af[i], wf[j], acc[i][j], 0, 0, 0);
    __syncthreads();
  }

  // epilogue: C/D layout col=lane&15, row=quad*4+reg (m89/m91)
#pragma unroll
  for (int i = 0; i < 4; ++i) {
    const int grow0 = bm * 128 + wm + i * 16 + quad * 4;
#pragma unroll
    for (int j = 0; j < 4; ++j) {
      const int gcol = bn * 128 + wn + j * 16 + fm;
      const float bb = (ACT == 1) ? bias[gcol] : 0.f;
#pragma unroll
      for (int r = 0; r < 4; ++r) {
        float v = acc[i][j][r] + bb;
        if (ACT == 1) v = 1.f / (1.f + __expf(-v));
        C[(size_t)(grow0 + r) * 1024 + gcol] = v;
      }
    }
  }
}

// ---------------- readout GEMM, MFMA hi/lo version (W pre-split into bf16 hi/lo) ----------------
// out[gr,e] = blend(gelu(LN(res)[gr,:] . ro_w[e,:] + bias[e]), ssm_recon, gate)
// A*W ~= Ah*Wh + Al*Wh + Ah*Wl (dropped Al*Wl ~2^-17). LN fused into A-staging.
__global__ __launch_bounds__(256) void gemm_readout_mfma(
    const float* __restrict__ A,      // reservoir states [M,1024]
    const unsigned short* __restrict__ Wh_g,  // bf16 hi of ro_w
    const unsigned short* __restrict__ Wl_g,  // bf16 lo of ro_w
    const float* __restrict__ bias,   // ro_bias
    const float2* __restrict__ lnst,  // per-row mean/rstd
    const float* __restrict__ lng, const float* __restrict__ lnb,
    const float* __restrict__ Avec,   // A[h]
    const float* __restrict__ cumd,   // within-chunk cumulative delta [M]
    const float* __restrict__ chH,    // per-chunk initial ssm state [B,16,1024]
    const float* __restrict__ gate,   // [M,1024]
    float* __restrict__ C)            // d_out: in = ssm local states, out = final
{
  __shared__ __align__(16) unsigned short Ah[128 * 40];
  __shared__ __align__(16) unsigned short Al[128 * 40];
  __shared__ __align__(16) unsigned short Wh[128 * 40];
  __shared__ __align__(16) unsigned short Wl[128 * 40];
  const int tid  = threadIdx.x;
  const int bn   = blockIdx.x & 7;
  const int bm   = blockIdx.x >> 3;
  const int wave = tid >> 6, lane = tid & 63;
  const int wm = (wave >> 1) * 64, wn = (wave & 1) * 64;
  const int fm = lane & 15, quad = lane >> 4;

  floatx4 acc[4][4];
#pragma unroll
  for (int i = 0; i < 4; ++i)
#pragma unroll
    for (int j = 0; j < 4; ++j) acc[i][j] = (floatx4){0.f, 0.f, 0.f, 0.f};

  const float* Abase = A + (size_t)bm * 128 * 1024;
  const unsigned short* Whb = Wh_g + (size_t)bn * 128 * 1024;
  const unsigned short* Wlb = Wl_g + (size_t)bn * 128 * 1024;

  // per-thread staged-row stats (row fixed per i across k-tiles)
  float2 st_i[4];
#pragma unroll
  for (int i = 0; i < 4; ++i) {
    const int q = tid + 256 * i;
    st_i[i] = lnst[bm * 128 + (q >> 3)];
  }

  for (int k0 = 0; k0 < 1024; k0 += 32) {
#pragma unroll
    for (int i = 0; i < 4; ++i) {
      const int q = tid + 256 * i;
      const int row = q >> 3, ch = q & 7;
      float4 a4 = *(const float4*)(Abase + (size_t)row * 1024 + k0 + ch * 4);
      const float4 g4 = *(const float4*)(lng + k0 + ch * 4);
      const float4 b4 = *(const float4*)(lnb + k0 + ch * 4);
      const float2 st = st_i[i];
      a4.x = (a4.x - st.x) * st.y * g4.x + b4.x;
      a4.y = (a4.y - st.x) * st.y * g4.y + b4.y;
      a4.z = (a4.z - st.x) * st.y * g4.z + b4.z;
      a4.w = (a4.w - st.x) * st.y * g4.w + b4.w;
      // hi/lo split of A
      const float av[4] = {a4.x, a4.y, a4.z, a4.w};
      unsigned ah[4]; float alr[4];
#pragma unroll
      for (int e = 0; e < 4; ++e) {
        ah[e] = (__float_as_uint(av[e]) + 0x8000u) & 0xFFFF0000u;
        alr[e] = av[e] - __uint_as_float(ah[e]);
      }
      uint2 pah, pal;
      pah.x = pack_hi16(ah[0], ah[1]); pah.y = pack_hi16(ah[2], ah[3]);
      pal.x = pack_bf16(alr[0], alr[1]); pal.y = pack_bf16(alr[2], alr[3]);
      *(uint2*)(&Ah[row * 40 + ch * 4]) = pah;
      *(uint2*)(&Al[row * 40 + ch * 4]) = pal;
      // W: pre-split, plain copies
      *(uint2*)(&Wh[row * 40 + ch * 4]) = *(const uint2*)(Whb + (size_t)row * 1024 + k0 + ch * 4);
      *(uint2*)(&Wl[row * 40 + ch * 4]) = *(const uint2*)(Wlb + (size_t)row * 1024 + k0 + ch * 4);
    }
    __syncthreads();
    short8 afh[4], afl[4], wfh[4], wfl[4];
#pragma unroll
    for (int i = 0; i < 4; ++i) {
      const int ao = (wm + i * 16 + fm) * 40 + quad * 8;
      const int wo = (wn + i * 16 + fm) * 40 + quad * 8;
      afh[i] = *(const short8*)(&Ah[ao]);
      afl[i] = *(const short8*)(&Al[ao]);
      wfh[i] = *(const short8*)(&Wh[wo]);
      wfl[i] = *(const short8*)(&Wl[wo]);
    }
#pragma unroll
    for (int i = 0; i < 4; ++i)
#pragma unroll
      for (int j = 0; j < 4; ++j) {
        acc[i][j] = __builtin_amdgcn_mfma_f32_16x16x32_bf16(afh[i], wfh[j], acc[i][j], 0, 0, 0);
        acc[i][j] = __builtin_amdgcn_mfma_f32_16x16x32_bf16(afl[i], wfh[j], acc[i][j], 0, 0, 0);
        acc[i][j] = __builtin_amdgcn_mfma_f32_16x16x32_bf16(afh[i], wfl[j], acc[i][j], 0, 0, 0);
      }
    __syncthreads();
  }

  // epilogue: C/D layout col=lane&15, row=quad*4+reg; gelu + ssm recon + gate blend
#pragma unroll
  for (int i = 0; i < 4; ++i) {
    const int grow0 = bm * 128 + wm + i * 16 + quad * 4;
    float cd_r[4];
    int hb_r[4];
#pragma unroll
    for (int r = 0; r < 4; ++r) {
      const int gr = grow0 + r;
      const int b = gr >> 11;           // gr = b*2048 + s
      const int c = (gr & 2047) >> 7;   // 128-step chunk
      cd_r[r] = cumd[gr];
      hb_r[r] = (b * 16 + c) << 10;
    }
#pragma unroll
    for (int j = 0; j < 4; ++j) {
      const int gcol = bn * 128 + wn + j * 16 + fm;
      const float Ae = Avec[gcol];
      const float bb = bias[gcol];
#pragma unroll
      for (int r = 0; r < 4; ++r) {
        const int gr = grow0 + r;
        const size_t off = (size_t)gr * 1024 + gcol;
        const float hin = chH[hb_r[r] + gcol];
        const float lcl = C[off];
        const float gt  = gate[off];
        float v = acc[i][j][r] + bb;
        v = 0.5f * v * (1.f + erff(v * 0.70710678118654752f));   // exact gelu
        const float p = __expf(Ae * cd_r[r]);                    // prod of A_bar over chunk prefix
        const float sst = lcl + p * hin;                         // true ssm state
        C[off] = v * gt + sst * (1.f - gt);
      }
    }
  }
}

// ---------------- reservoir scan v8: batch-partitioned (v7) + W pinned in VGPRs + 2-deep poll ----------------
// v7 post-mortem: VGPR_Count=88 < the 128 needed for w4r residency -> compiler sank the W
// loads into the step loop (legal: const __restrict__), putting 32 L2-latency loads on the
// serial chain every step. v8 pins w4r with asm keep-alives (values become asm outputs ->
// cannot be rematerialized from memory). Also: 2-deep speculative poll (two back-to-back
// loads per iteration) to cut detection granularity toward RT/2.
// Everything else identical to v7 (protocol, staging, single barrier, coalesced tail).
// Safety (per group): a thread stores tag s+1 only after barrier(s), which post-dates all its
// WG's tag-s polls; a WG overwrites tag-(s+1) words only after poll(s+2) success, certifying
// every group member passed barrier(s+1). Groups fully decoupled (disjoint hbuf slices).
__global__ __launch_bounds__(512, 2) void reservoir_scan_kernel(
    float* __restrict__ xin_res,       // [8][2048][1024]: in xin, out res states (in-place)
    const float* __restrict__ Wres,    // [1024][1024]
    unsigned* __restrict__ hbuf,       // [2][8][1024] packed words, zeroed before launch
    unsigned* __restrict__ unused)
{
  const int tid = threadIdx.x;
  const int wg  = blockIdx.x;          // 0..127
  const int go  = wg >> 4;             // batch group 0..7
  const int mem = wg & 15;             // member: rows mem*64..mem*64+63
  const int g   = tid >> 6;            // wave 0..7
  const int l   = tid & 63;
  const int c   = l & 7;               // k-chunk (128 k each)
  const int rl  = l >> 3;              // row within wave's 8
  const int row = mem * 64 + g * 8 + rl;   // global hidden row

  __shared__ __align__(16) float hs[2][1024];   // dbuf fp32 h (decoded from bf16 words)

  // ---- W registers: fp32, 8 rows x 1024 K per wave; lane holds its 128-k chunk,
  //      PRE-ROTATED (static index in compute) and PINNED (asm output -> no remat). ----
  float4 w4r[32];
  {
    const float* wrow = Wres + (size_t)row * 1024 + c * 128;
#pragma unroll
    for (int i = 0; i < 32; ++i) {
      w4r[i] = *(const float4*)(wrow + 4 * ((i + c) & 31));
      asm volatile("" : "+v"(w4r[i].x), "+v"(w4r[i].y), "+v"(w4r[i].z), "+v"(w4r[i].w));
    }
  }

  float hprev = 0.f;
  const unsigned long long tmask = 0x0000FFFF0000FFFFull;

  for (int s = 0; s < S_; ++s) {
    // ---- prefetch u before the poll (keep-alive pins issue order) ----
    const float u = xin_res[((size_t)go * S_ + s) * H_ + row];
    asm volatile("" :: "v"(u));

    // ---- poll h^s: ONE u64 per thread; 2 speculative loads per iteration ----
    const unsigned tag = (unsigned)s & 0xFFFFu;
    const unsigned long long tag2 = (unsigned long long)tag | ((unsigned long long)tag << 32);
    const unsigned long long* hp =
        (const unsigned long long*)(hbuf + (size_t)(s & 1) * 8192 + go * 1024) + tid;
    unsigned long long w;
    for (;;) {
      const unsigned long long wa = __hip_atomic_load(hp, __ATOMIC_RELAXED, __HIP_MEMORY_SCOPE_AGENT);
      const unsigned long long wb = __hip_atomic_load(hp, __ATOMIC_RELAXED, __HIP_MEMORY_SCOPE_AGENT);
      if (((wa ^ tag2) & tmask) == 0ull) { w = wa; break; }
      if (((wb ^ tag2) & tmask) == 0ull) { w = wb; break; }
    }

    // ---- stage as fp32 (mask off tag), one ds_write_b64 ----
    float2 hf;
    hf.x = __uint_as_float((unsigned)w & 0xFFFF0000u);
    hf.y = __uint_as_float((unsigned)(w >> 32) & 0xFFFF0000u);
    *(float2*)(&hs[s & 1][2 * tid]) = hf;
    __syncthreads();                   // the only barrier: staged; all polls done before
                                       // any tag-s+1 store below (safety inv.)

    // ---- fp32 matvec: lane's 128-k chunk, rotated reads (conflict-free, 8-way bcast) ----
    const float* hc = &hs[s & 1][c * 128];
    float p0 = 0.f, p1 = 0.f, p2 = 0.f, p3 = 0.f;
#pragma unroll
    for (int i = 0; i < 32; ++i) {
      const float4 h4 = *(const float4*)(hc + 4 * ((i + c) & 31));
      p0 += w4r[i].x * h4.x;
      p1 += w4r[i].y * h4.y;
      p2 += w4r[i].z * h4.z;
      p3 += w4r[i].w * h4.w;
    }
    float ps = (p0 + p1) + (p2 + p3);
    ps += __shfl_xor(ps, 1);
    ps += __shfl_xor(ps, 2);
    ps += __shfl_xor(ps, 4);           // full dot in all 8 c-lanes of the row group

    // ---- tanh, leak (all lanes; broadcast-consistent), store by c==0 lanes ----
    const float z  = u + ps;
    const float e  = __expf(2.f * z);                 // tanh(z) = 1 - 2/(e^{2z}+1)
    const float hn = 1.f - __fdividef(2.f, e + 1.f);  // saturates correctly
    const float hv = 0.95f * hn + 0.05f * hprev;
    hprev = hv;

    if (c == 0) {
      const unsigned word = ((__float_as_uint(hv) + 0x8000u) & 0xFFFF0000u)
                          | ((unsigned)(s + 1) & 0xFFFFu);
      __hip_atomic_store(hbuf + (size_t)((s + 1) & 1) * 8192 + go * 1024 + row, word,
                         __ATOMIC_RELAXED, __HIP_MEMORY_SCOPE_AGENT);
      xin_res[((size_t)go * S_ + s) * H_ + row] = hv;  // fp32 states, 32B-dense per wave
    }
    // no drain, no flag, no rendezvous — next iteration's poll is the wait
  }
}

// ---------------- SSM chunked scan ----------------
// within-chunk cumulative delta (tiny)
__global__ __launch_bounds__(128) void cumd_kernel(
    const float* __restrict__ delta, float* __restrict__ cumd)
{
  const int t = threadIdx.x;          // 128 = 8 batches * 16 chunks
  const int b = t >> 4, c = t & 15;
  const int base = b * S_ + c * 128;
  float acc = 0.f;
  for (int i = 0; i < 128; ++i) { acc += delta[base + i]; cumd[base + i] = acc; }
}

// phase A: per-chunk local scan, in-place Bx -> local states; store chunk products
__global__ __launch_bounds__(256) void ssm_partial_kernel(
    const float* __restrict__ delta, const float* __restrict__ Avec,
    float* __restrict__ bx, float* __restrict__ P)
{
  const int idx = blockIdx.x * 256 + threadIdx.x;
  const int h = idx & 1023;
  const int c = (idx >> 10) & 15;
  const int b = idx >> 14;
  const float Ah = Avec[h];
  const float inv = 1.f / (Ah + 1e-8f);
  const float* dp = delta + b * S_ + c * 128;
  float* xp = bx + ((size_t)(b * S_ + c * 128)) * H_ + h;
  float p = 1.f, hl = 0.f;
  for (int t = 0; t < 128; ++t) {
    const float a = __expf(Ah * dp[t]);
    const float bb = xp[(size_t)t * H_] * (1.f - a) * inv;
    hl = a * hl + bb;
    p *= a;
    xp[(size_t)t * H_] = hl;
  }
  P[(b * 16 + c) * 1024 + h] = p;
}

// phase B: sequential combine over 16 chunks -> per-chunk initial states
__global__ __launch_bounds__(256) void ssm_combine_kernel(
    const float* __restrict__ P, const float* __restrict__ local, float* __restrict__ Hin)
{
  const int idx = blockIdx.x * 256 + threadIdx.x;  // 8192
  const int h = idx & 1023;
  const int b = idx >> 10;
  float hh = 0.f;
#pragma unroll
  for (int c = 0; c < 16; ++c) {
    const int o = (b * 16 + c) * 1024 + h;
    Hin[o] = hh;
    hh = P[o] * hh + local[((size_t)(b * S_ + c * 128 + 127)) * H_ + h];
  }
}

// ---------------- host launch ----------------
extern "C" void kernel_launch(void* const* d_in, const int* in_sizes, int n_in,
                              void* d_out, int out_size, void* d_ws, size_t ws_size,
                              hipStream_t stream) {
  (void)in_sizes; (void)n_in; (void)out_size; (void)ws_size;
  const float* x      = (const float*)d_in[0];
  const float* W_in   = (const float*)d_in[1];
  const float* W_res  = (const float*)d_in[2];
  const float* norm_g = (const float*)d_in[3];
  const float* norm_b = (const float*)d_in[4];
  const float* dw     = (const float*)d_in[5];
  const float* db     = (const float*)d_in[6];
  const float* Avec   = (const float*)d_in[7];
  const float* B_w    = (const float*)d_in[8];
  const float* ro_g   = (const float*)d_in[9];
  const float* ro_b   = (const float*)d_in[10];
  const float* ro_w   = (const float*)d_in[11];
  const float* ro_bias= (const float*)d_in[12];
  const float* gate_w = (const float*)d_in[13];
  const float* gate_b = (const float*)d_in[14];
  float* out = (float*)d_out;
  float* ws  = (float*)d_ws;

  float*    buf0   = ws;                    // bf16 x_norm (first 32MB), later fp32 gate (64MB)
  float*    buf1   = ws + 16777216;         // xin -> reservoir states (in-place)
  float*    delta  = ws + 33554432;         // [M]
  float*    cumd   = ws + 33570816;         // [M]
  unsigned* hbuf   = (unsigned*)(ws + 33587200);  // [2][8][1024] packed words
  float2*   stats  = (float2*)(ws + 33603712);
  float*    chP    = ws + 33636480;         // [B,16,1024]
  float*    chH    = ws + 33767552;         // [B,16,1024]
  unsigned short* xnb = (unsigned short*)buf0;            // bf16 x_norm [M,1024]
  unsigned short* wib = (unsigned short*)(ws + 33898624); // bf16 W_in   [1024,1024]
  unsigned short* bwb = (unsigned short*)(ws + 34422912); // bf16 B_w
  unsigned short* roh = (unsigned short*)(ws + 34947200); // bf16 hi(ro_w)
  unsigned short* rol = (unsigned short*)(ws + 35471488); // bf16 lo(ro_w)

  // 0. weight conversions (once per launch, tiny)
  tobf16_kernel<<<1024, 256, 0, stream>>>(W_in, wib);
  tobf16_kernel<<<1024, 256, 0, stream>>>(B_w, bwb);
  splitw_kernel<<<1024, 256, 0, stream>>>(ro_w, roh, rol);
  // 1. layernorm -> bf16 x_norm + delta
  ln_delta_kernel<<<M_, 256, 0, stream>>>(x, norm_g, norm_b, dw, db, xnb, delta);
  // 2. xin = x_norm @ W_in^T   -> buf1   (bf16 x bf16 MFMA)
  gemm_bb<<<1024, 256, 0, stream>>>(xnb, wib, buf1);
  // 3. Bx = x_norm @ B_w^T     -> d_out (scratch)
  gemm_bb<<<1024, 256, 0, stream>>>(xnb, bwb, out);
  // 4. gate = sigmoid(x @ gate_w^T + gate_b) -> buf0 (xnb dead)   (fp32-input path)
  gemm_bf16_nt<1><<<1024, 256, 0, stream>>>(x, gate_w, gate_b, buf0);
  // 5. ssm chunked scan pieces (independent of reservoir)
  cumd_kernel<<<1, 128, 0, stream>>>(delta, cumd);
  ssm_partial_kernel<<<512, 256, 0, stream>>>(delta, Avec, out, chP);
  ssm_combine_kernel<<<32, 256, 0, stream>>>(chP, out, chH);
  // 6. reservoir scan (zero both parity buffers: word 0 == tag 0 | bf16(0))
  hipMemsetAsync(hbuf, 0, 2 * 8192 * sizeof(unsigned), stream);
  reservoir_scan_kernel<<<128, 512, 0, stream>>>(buf1, W_res, hbuf, nullptr);
  // 7. ro-layernorm stats
  rowstats_kernel<<<M_, 256, 0, stream>>>(buf1, stats);
  // 8. readout GEMM (MFMA hi/lo, pre-split W) + gelu + ssm recon + gate blend -> d_out
  gemm_readout_mfma<<<1024, 256, 0, stream>>>(buf1, roh, rol, ro_bias, stats, ro_g, ro_b,
                                              Avec, cumd, chH, buf0, out);
}

// Round 9
// 3988.639 us; speedup vs baseline: 1.1306x; 1.1306x over previous
//
#include <hip/hip_runtime.h>
#include <math.h>

#define B_ 8
#define S_ 2048
#define E_ 1024
#define H_ 1024
#define M_ 16384   // B_*S_

typedef __attribute__((ext_vector_type(8))) short short8;    // 8 bf16 = 4 VGPRs
typedef __attribute__((ext_vector_type(4))) float floatx4;

// ---------------- block-wide reduction of two floats (256 threads = 4 waves) ----------------
__device__ __forceinline__ void block_reduce2(float &a, float &b) {
#pragma unroll
  for (int off = 32; off > 0; off >>= 1) {
    a += __shfl_down(a, off);
    b += __shfl_down(b, off);
  }
  __shared__ float sa[4], sb[4];
  const int w = threadIdx.x >> 6;
  __syncthreads();                 // protects reuse across back-to-back calls
  if ((threadIdx.x & 63) == 0) { sa[w] = a; sb[w] = b; }
  __syncthreads();
  a = sa[0] + sa[1] + sa[2] + sa[3];
  b = sb[0] + sb[1] + sb[2] + sb[3];
}

__device__ __forceinline__ unsigned pack_bf16(float lo, float hi) {
  return __builtin_amdgcn_perm(__float_as_uint(hi) + 0x8000u,
                               __float_as_uint(lo) + 0x8000u, 0x07060302u);
}
// pack the hi16 of two u32 bit patterns: (hi16(a) in low half, hi16(b) in high half)
__device__ __forceinline__ unsigned pack_hi16(unsigned a, unsigned b) {
  return __builtin_amdgcn_perm(b, a, 0x07060302u);
}

// ---------------- LayerNorm(x) -> x_norm (bf16!), plus delta = softplus(x_norm . delta_w + db) ----------------
__global__ __launch_bounds__(256) void ln_delta_kernel(
    const float* __restrict__ x, const float* __restrict__ g, const float* __restrict__ bt,
    const float* __restrict__ dw, const float* __restrict__ db,
    unsigned short* __restrict__ xnb, float* __restrict__ delta)
{
  const int row = blockIdx.x;
  const int t = threadIdx.x;
  const float4 v = ((const float4*)(x + (size_t)row * E_))[t];
  float s1 = v.x + v.y + v.z + v.w;
  float s2 = v.x*v.x + v.y*v.y + v.z*v.z + v.w*v.w;
  block_reduce2(s1, s2);
  const float mean = s1 * (1.f / E_);
  const float var  = s2 * (1.f / E_) - mean * mean;
  const float rstd = rsqrtf(var + 1e-5f);
  const float4 g4 = ((const float4*)g)[t];
  const float4 b4 = ((const float4*)bt)[t];
  float4 o;
  o.x = (v.x - mean) * rstd * g4.x + b4.x;
  o.y = (v.y - mean) * rstd * g4.y + b4.y;
  o.z = (v.z - mean) * rstd * g4.z + b4.z;
  o.w = (v.w - mean) * rstd * g4.w + b4.w;
  uint2 p;
  p.x = pack_bf16(o.x, o.y); p.y = pack_bf16(o.z, o.w);
  ((uint2*)(xnb + (size_t)row * E_))[t] = p;       // bf16 x_norm (same rounding the GEMMs used)
  const float4 d4 = ((const float4*)dw)[t];
  float dd = o.x*d4.x + o.y*d4.y + o.z*d4.z + o.w*d4.w;   // delta stays fp32-accurate
  float dummy = 0.f;
  block_reduce2(dd, dummy);
  if (t == 0) {
    const float z = dd + db[0];
    delta[row] = (z > 20.f) ? z : log1pf(__expf(z));
  }
}

// ---------------- per-row mean/rstd of reservoir states (for fused ro-layernorm) ----------------
__global__ __launch_bounds__(256) void rowstats_kernel(
    const float* __restrict__ res, float2* __restrict__ st)
{
  const int row = blockIdx.x;
  const int t = threadIdx.x;
  const float4 v = ((const float4*)(res + (size_t)row * H_))[t];
  float s1 = v.x + v.y + v.z + v.w;
  float s2 = v.x*v.x + v.y*v.y + v.z*v.z + v.w*v.w;
  block_reduce2(s1, s2);
  if (t == 0) {
    const float m = s1 * (1.f / H_);
    const float var = s2 * (1.f / H_) - m * m;
    st[row] = make_float2(m, rsqrtf(var + 1e-5f));
  }
}

// ---------------- tiny converters (run once, off critical path) ----------------
__global__ __launch_bounds__(256) void tobf16_kernel(
    const float* __restrict__ s, unsigned short* __restrict__ d)
{
  const int i = blockIdx.x * 256 + threadIdx.x;
  const float4 v = ((const float4*)s)[i];
  uint2 p;
  p.x = pack_bf16(v.x, v.y); p.y = pack_bf16(v.z, v.w);
  ((uint2*)d)[i] = p;
}

__global__ __launch_bounds__(256) void splitw_kernel(
    const float* __restrict__ s, unsigned short* __restrict__ dh, unsigned short* __restrict__ dl)
{
  const int i = blockIdx.x * 256 + threadIdx.x;
  const float4 v = ((const float4*)s)[i];
  const float sv[4] = {v.x, v.y, v.z, v.w};
  unsigned h[4]; float l[4];
#pragma unroll
  for (int e = 0; e < 4; ++e) {
    h[e] = (__float_as_uint(sv[e]) + 0x8000u) & 0xFFFF0000u;
    l[e] = sv[e] - __uint_as_float(h[e]);
  }
  uint2 ph, pl;
  ph.x = pack_hi16(h[0], h[1]); ph.y = pack_hi16(h[2], h[3]);
  pl.x = pack_bf16(l[0], l[1]); pl.y = pack_bf16(l[2], l[3]);
  ((uint2*)dh)[i] = ph;
  ((uint2*)dl)[i] = pl;
}

// ---------------- bf16-input MFMA GEMM: C[M,N] = A[M,1024] @ W[N,1024]^T (A,W bf16) ----------------
__global__ __launch_bounds__(256) void gemm_bb(
    const unsigned short* __restrict__ A, const unsigned short* __restrict__ W,
    float* __restrict__ C)
{
  __shared__ __align__(16) unsigned short As[128 * 40];
  __shared__ __align__(16) unsigned short Ws[128 * 40];
  const int tid  = threadIdx.x;
  const int bn   = blockIdx.x & 7;
  const int bm   = blockIdx.x >> 3;
  const int wave = tid >> 6, lane = tid & 63;
  const int wm = (wave >> 1) * 64, wn = (wave & 1) * 64;
  const int fm = lane & 15, quad = lane >> 4;

  floatx4 acc[4][4];
#pragma unroll
  for (int i = 0; i < 4; ++i)
#pragma unroll
    for (int j = 0; j < 4; ++j) acc[i][j] = (floatx4){0.f, 0.f, 0.f, 0.f};

  const unsigned short* Abase = A + (size_t)bm * 128 * 1024;
  const unsigned short* Wbase = W + (size_t)bn * 128 * 1024;

  for (int k0 = 0; k0 < 1024; k0 += 32) {
    uint2 a2[4], w2[4];
#pragma unroll
    for (int i = 0; i < 4; ++i) {
      const int q = tid + 256 * i;
      const int row = q >> 3, ch = q & 7;
      a2[i] = *(const uint2*)(Abase + (size_t)row * 1024 + k0 + ch * 4);
      w2[i] = *(const uint2*)(Wbase + (size_t)row * 1024 + k0 + ch * 4);
    }
#pragma unroll
    for (int i = 0; i < 4; ++i) {
      const int q = tid + 256 * i;
      const int row = q >> 3, ch = q & 7;
      *(uint2*)(&As[row * 40 + ch * 4]) = a2[i];
      *(uint2*)(&Ws[row * 40 + ch * 4]) = w2[i];
    }
    __syncthreads();
    short8 af[4], wf[4];
#pragma unroll
    for (int i = 0; i < 4; ++i) {
      af[i] = *(const short8*)(&As[(wm + i * 16 + fm) * 40 + quad * 8]);
      wf[i] = *(const short8*)(&Ws[(wn + i * 16 + fm) * 40 + quad * 8]);
    }
#pragma unroll
    for (int i = 0; i < 4; ++i)
#pragma unroll
      for (int j = 0; j < 4; ++j)
        acc[i][j] = __builtin_amdgcn_mfma_f32_16x16x32_bf16(af[i], wf[j], acc[i][j], 0, 0, 0);
    __syncthreads();
  }

  // epilogue: C/D layout col=lane&15, row=quad*4+reg (m89/m91)
#pragma unroll
  for (int i = 0; i < 4; ++i) {
    const int grow0 = bm * 128 + wm + i * 16 + quad * 4;
#pragma unroll
    for (int j = 0; j < 4; ++j) {
      const int gcol = bn * 128 + wn + j * 16 + fm;
#pragma unroll
      for (int r = 0; r < 4; ++r)
        C[(size_t)(grow0 + r) * 1024 + gcol] = acc[i][j][r];
    }
  }
}

// ---------------- fp32-input bf16 MFMA GEMM with sigmoid (gate) ----------------
template<int ACT>
__global__ __launch_bounds__(256) void gemm_bf16_nt(
    const float* __restrict__ A, const float* __restrict__ W,
    const float* __restrict__ bias, float* __restrict__ C)
{
  __shared__ __align__(16) unsigned short As[128 * 40];
  __shared__ __align__(16) unsigned short Ws[128 * 40];
  const int tid  = threadIdx.x;
  const int bn   = blockIdx.x & 7;
  const int bm   = blockIdx.x >> 3;
  const int wave = tid >> 6, lane = tid & 63;
  const int wm = (wave >> 1) * 64, wn = (wave & 1) * 64;
  const int fm = lane & 15, quad = lane >> 4;

  floatx4 acc[4][4];
#pragma unroll
  for (int i = 0; i < 4; ++i)
#pragma unroll
    for (int j = 0; j < 4; ++j) acc[i][j] = (floatx4){0.f, 0.f, 0.f, 0.f};

  const float* Abase = A + (size_t)bm * 128 * 1024;
  const float* Wbase = W + (size_t)bn * 128 * 1024;

  for (int k0 = 0; k0 < 1024; k0 += 32) {
    float4 a4[4], w4[4];
#pragma unroll
    for (int i = 0; i < 4; ++i) {
      const int q = tid + 256 * i;
      const int row = q >> 3, ch = q & 7;
      a4[i] = *(const float4*)(Abase + (size_t)row * 1024 + k0 + ch * 4);
      w4[i] = *(const float4*)(Wbase + (size_t)row * 1024 + k0 + ch * 4);
    }
#pragma unroll
    for (int i = 0; i < 4; ++i) {
      const int q = tid + 256 * i;
      const int row = q >> 3, ch = q & 7;
      uint2 pa, pw;
      pa.x = pack_bf16(a4[i].x, a4[i].y); pa.y = pack_bf16(a4[i].z, a4[i].w);
      pw.x = pack_bf16(w4[i].x, w4[i].y); pw.y = pack_bf16(w4[i].z, w4[i].w);
      *(uint2*)(&As[row * 40 + ch * 4]) = pa;
      *(uint2*)(&Ws[row * 40 + ch * 4]) = pw;
    }
    __syncthreads();
    short8 af[4], wf[4];
#pragma unroll
    for (int i = 0; i < 4; ++i) {
      af[i] = *(const short8*)(&As[(wm + i * 16 + fm) * 40 + quad * 8]);
      wf[i] = *(const short8*)(&Ws[(wn + i * 16 + fm) * 40 + quad * 8]);
    }
#pragma unroll
    for (int i = 0; i < 4; ++i)
#pragma unroll
      for (int j = 0; j < 4; ++j)
        acc[i][j] = __builtin_amdgcn_mfma_f32_16x16x32_bf16(af[i], wf[j], acc[i][j], 0, 0, 0);
    __syncthreads();
  }

  // epilogue: C/D layout col=lane&15, row=quad*4+reg (m89/m91)
#pragma unroll
  for (int i = 0; i < 4; ++i) {
    const int grow0 = bm * 128 + wm + i * 16 + quad * 4;
#pragma unroll
    for (int j = 0; j < 4; ++j) {
      const int gcol = bn * 128 + wn + j * 16 + fm;
      const float bb = (ACT == 1) ? bias[gcol] : 0.f;
#pragma unroll
      for (int r = 0; r < 4; ++r) {
        float v = acc[i][j][r] + bb;
        if (ACT == 1) v = 1.f / (1.f + __expf(-v));
        C[(size_t)(grow0 + r) * 1024 + gcol] = v;
      }
    }
  }
}

// ---------------- readout GEMM, MFMA hi/lo version (W pre-split into bf16 hi/lo) ----------------
// out[gr,e] = blend(gelu(LN(res)[gr,:] . ro_w[e,:] + bias[e]), ssm_recon, gate)
// A*W ~= Ah*Wh + Al*Wh + Ah*Wl (dropped Al*Wl ~2^-17). LN fused into A-staging.
__global__ __launch_bounds__(256) void gemm_readout_mfma(
    const float* __restrict__ A,      // reservoir states [M,1024]
    const unsigned short* __restrict__ Wh_g,  // bf16 hi of ro_w
    const unsigned short* __restrict__ Wl_g,  // bf16 lo of ro_w
    const float* __restrict__ bias,   // ro_bias
    const float2* __restrict__ lnst,  // per-row mean/rstd
    const float* __restrict__ lng, const float* __restrict__ lnb,
    const float* __restrict__ Avec,   // A[h]
    const float* __restrict__ cumd,   // within-chunk cumulative delta [M]
    const float* __restrict__ chH,    // per-chunk initial ssm state [B,16,1024]
    const float* __restrict__ gate,   // [M,1024]
    float* __restrict__ C)            // d_out: in = ssm local states, out = final
{
  __shared__ __align__(16) unsigned short Ah[128 * 40];
  __shared__ __align__(16) unsigned short Al[128 * 40];
  __shared__ __align__(16) unsigned short Wh[128 * 40];
  __shared__ __align__(16) unsigned short Wl[128 * 40];
  const int tid  = threadIdx.x;
  const int bn   = blockIdx.x & 7;
  const int bm   = blockIdx.x >> 3;
  const int wave = tid >> 6, lane = tid & 63;
  const int wm = (wave >> 1) * 64, wn = (wave & 1) * 64;
  const int fm = lane & 15, quad = lane >> 4;

  floatx4 acc[4][4];
#pragma unroll
  for (int i = 0; i < 4; ++i)
#pragma unroll
    for (int j = 0; j < 4; ++j) acc[i][j] = (floatx4){0.f, 0.f, 0.f, 0.f};

  const float* Abase = A + (size_t)bm * 128 * 1024;
  const unsigned short* Whb = Wh_g + (size_t)bn * 128 * 1024;
  const unsigned short* Wlb = Wl_g + (size_t)bn * 128 * 1024;

  // per-thread staged-row stats (row fixed per i across k-tiles)
  float2 st_i[4];
#pragma unroll
  for (int i = 0; i < 4; ++i) {
    const int q = tid + 256 * i;
    st_i[i] = lnst[bm * 128 + (q >> 3)];
  }

  for (int k0 = 0; k0 < 1024; k0 += 32) {
#pragma unroll
    for (int i = 0; i < 4; ++i) {
      const int q = tid + 256 * i;
      const int row = q >> 3, ch = q & 7;
      float4 a4 = *(const float4*)(Abase + (size_t)row * 1024 + k0 + ch * 4);
      const float4 g4 = *(const float4*)(lng + k0 + ch * 4);
      const float4 b4 = *(const float4*)(lnb + k0 + ch * 4);
      const float2 st = st_i[i];
      a4.x = (a4.x - st.x) * st.y * g4.x + b4.x;
      a4.y = (a4.y - st.x) * st.y * g4.y + b4.y;
      a4.z = (a4.z - st.x) * st.y * g4.z + b4.z;
      a4.w = (a4.w - st.x) * st.y * g4.w + b4.w;
      // hi/lo split of A
      const float av[4] = {a4.x, a4.y, a4.z, a4.w};
      unsigned ah[4]; float alr[4];
#pragma unroll
      for (int e = 0; e < 4; ++e) {
        ah[e] = (__float_as_uint(av[e]) + 0x8000u) & 0xFFFF0000u;
        alr[e] = av[e] - __uint_as_float(ah[e]);
      }
      uint2 pah, pal;
      pah.x = pack_hi16(ah[0], ah[1]); pah.y = pack_hi16(ah[2], ah[3]);
      pal.x = pack_bf16(alr[0], alr[1]); pal.y = pack_bf16(alr[2], alr[3]);
      *(uint2*)(&Ah[row * 40 + ch * 4]) = pah;
      *(uint2*)(&Al[row * 40 + ch * 4]) = pal;
      // W: pre-split, plain copies
      *(uint2*)(&Wh[row * 40 + ch * 4]) = *(const uint2*)(Whb + (size_t)row * 1024 + k0 + ch * 4);
      *(uint2*)(&Wl[row * 40 + ch * 4]) = *(const uint2*)(Wlb + (size_t)row * 1024 + k0 + ch * 4);
    }
    __syncthreads();
    short8 afh[4], afl[4], wfh[4], wfl[4];
#pragma unroll
    for (int i = 0; i < 4; ++i) {
      const int ao = (wm + i * 16 + fm) * 40 + quad * 8;
      const int wo = (wn + i * 16 + fm) * 40 + quad * 8;
      afh[i] = *(const short8*)(&Ah[ao]);
      afl[i] = *(const short8*)(&Al[ao]);
      wfh[i] = *(const short8*)(&Wh[wo]);
      wfl[i] = *(const short8*)(&Wl[wo]);
    }
#pragma unroll
    for (int i = 0; i < 4; ++i)
#pragma unroll
      for (int j = 0; j < 4; ++j) {
        acc[i][j] = __builtin_amdgcn_mfma_f32_16x16x32_bf16(afh[i], wfh[j], acc[i][j], 0, 0, 0);
        acc[i][j] = __builtin_amdgcn_mfma_f32_16x16x32_bf16(afl[i], wfh[j], acc[i][j], 0, 0, 0);
        acc[i][j] = __builtin_amdgcn_mfma_f32_16x16x32_bf16(afh[i], wfl[j], acc[i][j], 0, 0, 0);
      }
    __syncthreads();
  }

  // epilogue: C/D layout col=lane&15, row=quad*4+reg; gelu + ssm recon + gate blend
#pragma unroll
  for (int i = 0; i < 4; ++i) {
    const int grow0 = bm * 128 + wm + i * 16 + quad * 4;
    float cd_r[4];
    int hb_r[4];
#pragma unroll
    for (int r = 0; r < 4; ++r) {
      const int gr = grow0 + r;
      const int b = gr >> 11;           // gr = b*2048 + s
      const int c = (gr & 2047) >> 7;   // 128-step chunk
      cd_r[r] = cumd[gr];
      hb_r[r] = (b * 16 + c) << 10;
    }
#pragma unroll
    for (int j = 0; j < 4; ++j) {
      const int gcol = bn * 128 + wn + j * 16 + fm;
      const float Ae = Avec[gcol];
      const float bb = bias[gcol];
#pragma unroll
      for (int r = 0; r < 4; ++r) {
        const int gr = grow0 + r;
        const size_t off = (size_t)gr * 1024 + gcol;
        const float hin = chH[hb_r[r] + gcol];
        const float lcl = C[off];
        const float gt  = gate[off];
        float v = acc[i][j][r] + bb;
        v = 0.5f * v * (1.f + erff(v * 0.70710678118654752f));   // exact gelu
        const float p = __expf(Ae * cd_r[r]);                    // prod of A_bar over chunk prefix
        const float sst = lcl + p * hin;                         // true ssm state
        C[off] = v * gt + sst * (1.f - gt);
      }
    }
  }
}

// ---------------- reservoir scan v9: batch-partitioned + wide-lane LDS reads + butterfly reduce ----------------
// v8 post-mortem: 2-deep poll regressed (compiler drains both loads before checking) -> revert
// to single-load poll. W residency was never broken (r7 FETCH=299MB ~ algorithmic; a per-step
// refetch would be ~68GB) -> drop the asm pin. The REAL compute cost in v7 was LDS-unit
// serialization: 32 ds_read_b128/thread/step = 256 LDS insts/CU/step with only 8 distinct
// 16B lines per instruction (8-fold same-address broadcast). v9 remaps:
//   * lane l = 16-k chunk (k = 16l..16l+15): 4x ds_read_b128/step, every lane a DISTINCT line.
//   * wave g = 8 rows; W = 8 rows x 16 k = 128 floats/thread (same budget as v7).
//   * XOR line swizzle P = L ^ ((L>>5)&7) (bijective) spreads each instruction's 64 lines
//     evenly over the 8 bank-groups (floor for 1KB/inst).
//   * 8-acc butterfly reduce-scatter: 3 select+shfl levels scatter rows onto lane bits 0..2,
//     3 tree levels (xor 8/16/32) finish; lanes 0..7 hold rows 0..7 -> 32B-contiguous tail.
//   LDS insts/CU/step: 264 -> 40.
// Protocol unchanged (per-batch groups of 16 WGs, disjoint hbuf slices, self-certifying
// words bf16(h)<<16|tag, relaxed AGENT-scope atomics, parity buffers, zeroed before launch).
// Safety (per group): a thread stores tag s+1 only after barrier(s), which post-dates all its
// WG's tag-s polls; a WG overwrites tag-s words (tag s+2) only after poll(s+1) success,
// certifying every group member passed barrier(s). LDS dbuf reuse separated by barrier(s+1).
__global__ __launch_bounds__(512, 2) void reservoir_scan_kernel(
    float* __restrict__ xin_res,       // [8][2048][1024]: in xin, out res states (in-place)
    const float* __restrict__ Wres,    // [1024][1024]
    unsigned* __restrict__ hbuf,       // [2][8][1024] packed words, zeroed before launch
    unsigned* __restrict__ unused)
{
  const int tid = threadIdx.x;
  const int wg  = blockIdx.x;          // 0..127
  const int go  = wg >> 4;             // batch group 0..7
  const int mem = wg & 15;             // member: rows mem*64..mem*64+63
  const int g   = tid >> 6;            // wave 0..7
  const int l   = tid & 63;
  const int row8 = mem * 64 + g * 8;   // wave's 8-row base

  __shared__ __align__(16) float hs[2][1024];   // dbuf fp32 h, XOR line-swizzled

  // ---- W registers: 8 rows x 16 k per thread (k = 16l .. 16l+15) ----
  float4 w4[8][4];
  {
#pragma unroll
    for (int r = 0; r < 8; ++r) {
      const float* wrow = Wres + (size_t)(row8 + r) * 1024 + l * 16;
#pragma unroll
      for (int j = 0; j < 4; ++j) w4[r][j] = *(const float4*)(wrow + 4 * j);
    }
  }

  const int m0 = l & 1, m1 = (l >> 1) & 1, m2 = (l >> 2) & 1;
  const int myrow = row8 + (l & 7);    // row this lane finalizes (lanes 8+ duplicate)
  float hprev = 0.f;
  const unsigned long long tmask = 0x0000FFFF0000FFFFull;

  // staging: thread writes floats (2*tid, 2*tid+1) -> logical line Lw=tid>>1, swizzled
  const int Pw = (tid >> 1) ^ ((tid >> 6) & 7);
  const int wofs = Pw * 4 + (tid & 1) * 2;

  for (int s = 0; s < S_; ++s) {
    // ---- prefetch u before the poll (keep-alive pins issue order) ----
    const float u = xin_res[((size_t)go * S_ + s) * H_ + myrow];
    asm volatile("" :: "v"(u));

    // ---- poll h^s: ONE u64 per thread (rows 2*tid, 2*tid+1 of this group) ----
    const unsigned tag = (unsigned)s & 0xFFFFu;
    const unsigned long long tag2 = (unsigned long long)tag | ((unsigned long long)tag << 32);
    const unsigned long long* hp =
        (const unsigned long long*)(hbuf + (size_t)(s & 1) * 8192 + go * 1024) + tid;
    unsigned long long w;
    for (;;) {
      w = __hip_atomic_load(hp, __ATOMIC_RELAXED, __HIP_MEMORY_SCOPE_AGENT);
      if (((w ^ tag2) & tmask) == 0ull) break;
    }

    // ---- stage as fp32 (mask off tag), one ds_write_b64 to swizzled line ----
    float2 hf;
    hf.x = __uint_as_float((unsigned)w & 0xFFFF0000u);
    hf.y = __uint_as_float((unsigned)(w >> 32) & 0xFFFF0000u);
    *(float2*)(&hs[s & 1][wofs]) = hf;
    __syncthreads();                   // the only barrier: staged; all polls done before
                                       // any tag-s+1 store below (safety inv.)

    // ---- matvec: 8 rows x 16 k per thread; 4 wide ds_read_b128 (distinct line/lane) ----
    const float* hbse = hs[s & 1];
    float acc0 = 0.f, acc1 = 0.f, acc2 = 0.f, acc3 = 0.f;
    float acc4 = 0.f, acc5 = 0.f, acc6 = 0.f, acc7 = 0.f;
#pragma unroll
    for (int j = 0; j < 4; ++j) {
      const int P = (4 * l + j) ^ ((l >> 3) & 7);
      const float4 h4 = *(const float4*)(hbse + P * 4);
      acc0 += w4[0][j].x * h4.x + w4[0][j].y * h4.y + w4[0][j].z * h4.z + w4[0][j].w * h4.w;
      acc1 += w4[1][j].x * h4.x + w4[1][j].y * h4.y + w4[1][j].z * h4.z + w4[1][j].w * h4.w;
      acc2 += w4[2][j].x * h4.x + w4[2][j].y * h4.y + w4[2][j].z * h4.z + w4[2][j].w * h4.w;
      acc3 += w4[3][j].x * h4.x + w4[3][j].y * h4.y + w4[3][j].z * h4.z + w4[3][j].w * h4.w;
      acc4 += w4[4][j].x * h4.x + w4[4][j].y * h4.y + w4[4][j].z * h4.z + w4[4][j].w * h4.w;
      acc5 += w4[5][j].x * h4.x + w4[5][j].y * h4.y + w4[5][j].z * h4.z + w4[5][j].w * h4.w;
      acc6 += w4[6][j].x * h4.x + w4[6][j].y * h4.y + w4[6][j].z * h4.z + w4[6][j].w * h4.w;
      acc7 += w4[7][j].x * h4.x + w4[7][j].y * h4.y + w4[7][j].z * h4.z + w4[7][j].w * h4.w;
    }

    // ---- butterfly reduce-scatter: rows onto lane bits 0..2, then tree over bits 3..5 ----
    // level 0 (xor 1): keep rows with bit0==m0; partner sends its non-kept slot.
    float v0 = (m0 ? acc1 : acc0) + __shfl_xor(m0 ? acc0 : acc1, 1);
    float v1 = (m0 ? acc3 : acc2) + __shfl_xor(m0 ? acc2 : acc3, 1);
    float v2 = (m0 ? acc5 : acc4) + __shfl_xor(m0 ? acc4 : acc5, 1);
    float v3 = (m0 ? acc7 : acc6) + __shfl_xor(m0 ? acc6 : acc7, 1);
    // level 1 (xor 2)
    float u0 = (m1 ? v1 : v0) + __shfl_xor(m1 ? v0 : v1, 2);
    float u1 = (m1 ? v3 : v2) + __shfl_xor(m1 ? v2 : v3, 2);
    // level 2 (xor 4)
    float ps = (m2 ? u1 : u0) + __shfl_xor(m2 ? u0 : u1, 4);
    // tree over lane bits 3..5: lane l -> full dot of row (l&7)
    ps += __shfl_xor(ps, 8);
    ps += __shfl_xor(ps, 16);
    ps += __shfl_xor(ps, 32);

    // ---- tanh, leak (all lanes compute; duplicates consistent), lanes 0..7 store ----
    const float z  = u + ps;
    const float e  = __expf(2.f * z);                 // tanh(z) = 1 - 2/(e^{2z}+1)
    const float hn = 1.f - __fdividef(2.f, e + 1.f);  // saturates correctly
    const float hv = 0.95f * hn + 0.05f * hprev;
    hprev = hv;

    if (l < 8) {
      const unsigned word = ((__float_as_uint(hv) + 0x8000u) & 0xFFFF0000u)
                          | ((unsigned)(s + 1) & 0xFFFFu);
      __hip_atomic_store(hbuf + (size_t)((s + 1) & 1) * 8192 + go * 1024 + myrow, word,
                         __ATOMIC_RELAXED, __HIP_MEMORY_SCOPE_AGENT);
      xin_res[((size_t)go * S_ + s) * H_ + myrow] = hv;  // fp32 states, 32B-dense per wave
    }
    // no drain, no flag, no rendezvous — next iteration's poll is the wait
  }
}

// ---------------- SSM chunked scan ----------------
// within-chunk cumulative delta (tiny)
__global__ __launch_bounds__(128) void cumd_kernel(
    const float* __restrict__ delta, float* __restrict__ cumd)
{
  const int t = threadIdx.x;          // 128 = 8 batches * 16 chunks
  const int b = t >> 4, c = t & 15;
  const int base = b * S_ + c * 128;
  float acc = 0.f;
  for (int i = 0; i < 128; ++i) { acc += delta[base + i]; cumd[base + i] = acc; }
}

// phase A: per-chunk local scan, in-place Bx -> local states; store chunk products
__global__ __launch_bounds__(256) void ssm_partial_kernel(
    const float* __restrict__ delta, const float* __restrict__ Avec,
    float* __restrict__ bx, float* __restrict__ P)
{
  const int idx = blockIdx.x * 256 + threadIdx.x;
  const int h = idx & 1023;
  const int c = (idx >> 10) & 15;
  const int b = idx >> 14;
  const float Ah = Avec[h];
  const float inv = 1.f / (Ah + 1e-8f);
  const float* dp = delta + b * S_ + c * 128;
  float* xp = bx + ((size_t)(b * S_ + c * 128)) * H_ + h;
  float p = 1.f, hl = 0.f;
  for (int t = 0; t < 128; ++t) {
    const float a = __expf(Ah * dp[t]);
    const float bb = xp[(size_t)t * H_] * (1.f - a) * inv;
    hl = a * hl + bb;
    p *= a;
    xp[(size_t)t * H_] = hl;
  }
  P[(b * 16 + c) * 1024 + h] = p;
}

// phase B: sequential combine over 16 chunks -> per-chunk initial states
__global__ __launch_bounds__(256) void ssm_combine_kernel(
    const float* __restrict__ P, const float* __restrict__ local, float* __restrict__ Hin)
{
  const int idx = blockIdx.x * 256 + threadIdx.x;  // 8192
  const int h = idx & 1023;
  const int b = idx >> 10;
  float hh = 0.f;
#pragma unroll
  for (int c = 0; c < 16; ++c) {
    const int o = (b * 16 + c) * 1024 + h;
    Hin[o] = hh;
    hh = P[o] * hh + local[((size_t)(b * S_ + c * 128 + 127)) * H_ + h];
  }
}

// ---------------- host launch ----------------
extern "C" void kernel_launch(void* const* d_in, const int* in_sizes, int n_in,
                              void* d_out, int out_size, void* d_ws, size_t ws_size,
                              hipStream_t stream) {
  (void)in_sizes; (void)n_in; (void)out_size; (void)ws_size;
  const float* x      = (const float*)d_in[0];
  const float* W_in   = (const float*)d_in[1];
  const float* W_res  = (const float*)d_in[2];
  const float* norm_g = (const float*)d_in[3];
  const float* norm_b = (const float*)d_in[4];
  const float* dw     = (const float*)d_in[5];
  const float* db     = (const float*)d_in[6];
  const float* Avec   = (const float*)d_in[7];
  const float* B_w    = (const float*)d_in[8];
  const float* ro_g   = (const float*)d_in[9];
  const float* ro_b   = (const float*)d_in[10];
  const float* ro_w   = (const float*)d_in[11];
  const float* ro_bias= (const float*)d_in[12];
  const float* gate_w = (const float*)d_in[13];
  const float* gate_b = (const float*)d_in[14];
  float* out = (float*)d_out;
  float* ws  = (float*)d_ws;

  float*    buf0   = ws;                    // bf16 x_norm (first 32MB), later fp32 gate (64MB)
  float*    buf1   = ws + 16777216;         // xin -> reservoir states (in-place)
  float*    delta  = ws + 33554432;         // [M]
  float*    cumd   = ws + 33570816;         // [M]
  unsigned* hbuf   = (unsigned*)(ws + 33587200);  // [2][8][1024] packed words
  float2*   stats  = (float2*)(ws + 33603712);
  float*    chP    = ws + 33636480;         // [B,16,1024]
  float*    chH    = ws + 33767552;         // [B,16,1024]
  unsigned short* xnb = (unsigned short*)buf0;            // bf16 x_norm [M,1024]
  unsigned short* wib = (unsigned short*)(ws + 33898624); // bf16 W_in   [1024,1024]
  unsigned short* bwb = (unsigned short*)(ws + 34422912); // bf16 B_w
  unsigned short* roh = (unsigned short*)(ws + 34947200); // bf16 hi(ro_w)
  unsigned short* rol = (unsigned short*)(ws + 35471488); // bf16 lo(ro_w)

  // 0. weight conversions (once per launch, tiny)
  tobf16_kernel<<<1024, 256, 0, stream>>>(W_in, wib);
  tobf16_kernel<<<1024, 256, 0, stream>>>(B_w, bwb);
  splitw_kernel<<<1024, 256, 0, stream>>>(ro_w, roh, rol);
  // 1. layernorm -> bf16 x_norm + delta
  ln_delta_kernel<<<M_, 256, 0, stream>>>(x, norm_g, norm_b, dw, db, xnb, delta);
  // 2. xin = x_norm @ W_in^T   -> buf1   (bf16 x bf16 MFMA)
  gemm_bb<<<1024, 256, 0, stream>>>(xnb, wib, buf1);
  // 3. Bx = x_norm @ B_w^T     -> d_out (scratch)
  gemm_bb<<<1024, 256, 0, stream>>>(xnb, bwb, out);
  // 4. gate = sigmoid(x @ gate_w^T + gate_b) -> buf0 (xnb dead)   (fp32-input path)
  gemm_bf16_nt<1><<<1024, 256, 0, stream>>>(x, gate_w, gate_b, buf0);
  // 5. ssm chunked scan pieces (independent of reservoir)
  cumd_kernel<<<1, 128, 0, stream>>>(delta, cumd);
  ssm_partial_kernel<<<512, 256, 0, stream>>>(delta, Avec, out, chP);
  ssm_combine_kernel<<<32, 256, 0, stream>>>(chP, out, chH);
  // 6. reservoir scan (zero both parity buffers: word 0 == tag 0 | bf16(0))
  hipMemsetAsync(hbuf, 0, 2 * 8192 * sizeof(unsigned), stream);
  reservoir_scan_kernel<<<128, 512, 0, stream>>>(buf1, W_res, hbuf, nullptr);
  // 7. ro-layernorm stats
  rowstats_kernel<<<M_, 256, 0, stream>>>(buf1, stats);
  // 8. readout GEMM (MFMA hi/lo, pre-split W) + gelu + ssm recon + gate blend -> d_out
  gemm_readout_mfma<<<1024, 256, 0, stream>>>(buf1, roh, rol, ro_bias, stats, ro_g, ro_b,
                                              Avec, cumd, chH, buf0, out);
}

// Round 10
// 3848.140 us; speedup vs baseline: 1.1719x; 1.0365x over previous
//
#include <hip/hip_runtime.h>
#include <math.h>

#define B_ 8
#define S_ 2048
#define E_ 1024
#define H_ 1024
#define M_ 16384   // B_*S_

typedef __attribute__((ext_vector_type(8))) short short8;    // 8 bf16 = 4 VGPRs
typedef __attribute__((ext_vector_type(4))) float floatx4;

// ---------------- block-wide reduction of two floats (256 threads = 4 waves) ----------------
__device__ __forceinline__ void block_reduce2(float &a, float &b) {
#pragma unroll
  for (int off = 32; off > 0; off >>= 1) {
    a += __shfl_down(a, off);
    b += __shfl_down(b, off);
  }
  __shared__ float sa[4], sb[4];
  const int w = threadIdx.x >> 6;
  __syncthreads();                 // protects reuse across back-to-back calls
  if ((threadIdx.x & 63) == 0) { sa[w] = a; sb[w] = b; }
  __syncthreads();
  a = sa[0] + sa[1] + sa[2] + sa[3];
  b = sb[0] + sb[1] + sb[2] + sb[3];
}

__device__ __forceinline__ unsigned pack_bf16(float lo, float hi) {
  return __builtin_amdgcn_perm(__float_as_uint(hi) + 0x8000u,
                               __float_as_uint(lo) + 0x8000u, 0x07060302u);
}
// pack the hi16 of two u32 bit patterns: (hi16(a) in low half, hi16(b) in high half)
__device__ __forceinline__ unsigned pack_hi16(unsigned a, unsigned b) {
  return __builtin_amdgcn_perm(b, a, 0x07060302u);
}

// ---------------- LayerNorm(x) -> x_norm (bf16!), plus delta = softplus(x_norm . delta_w + db) ----------------
__global__ __launch_bounds__(256) void ln_delta_kernel(
    const float* __restrict__ x, const float* __restrict__ g, const float* __restrict__ bt,
    const float* __restrict__ dw, const float* __restrict__ db,
    unsigned short* __restrict__ xnb, float* __restrict__ delta)
{
  const int row = blockIdx.x;
  const int t = threadIdx.x;
  const float4 v = ((const float4*)(x + (size_t)row * E_))[t];
  float s1 = v.x + v.y + v.z + v.w;
  float s2 = v.x*v.x + v.y*v.y + v.z*v.z + v.w*v.w;
  block_reduce2(s1, s2);
  const float mean = s1 * (1.f / E_);
  const float var  = s2 * (1.f / E_) - mean * mean;
  const float rstd = rsqrtf(var + 1e-5f);
  const float4 g4 = ((const float4*)g)[t];
  const float4 b4 = ((const float4*)bt)[t];
  float4 o;
  o.x = (v.x - mean) * rstd * g4.x + b4.x;
  o.y = (v.y - mean) * rstd * g4.y + b4.y;
  o.z = (v.z - mean) * rstd * g4.z + b4.z;
  o.w = (v.w - mean) * rstd * g4.w + b4.w;
  uint2 p;
  p.x = pack_bf16(o.x, o.y); p.y = pack_bf16(o.z, o.w);
  ((uint2*)(xnb + (size_t)row * E_))[t] = p;       // bf16 x_norm (same rounding the GEMMs used)
  const float4 d4 = ((const float4*)dw)[t];
  float dd = o.x*d4.x + o.y*d4.y + o.z*d4.z + o.w*d4.w;   // delta stays fp32-accurate
  float dummy = 0.f;
  block_reduce2(dd, dummy);
  if (t == 0) {
    const float z = dd + db[0];
    delta[row] = (z > 20.f) ? z : log1pf(__expf(z));
  }
}

// ---------------- per-row mean/rstd of reservoir states (for fused ro-layernorm) ----------------
__global__ __launch_bounds__(256) void rowstats_kernel(
    const float* __restrict__ res, float2* __restrict__ st)
{
  const int row = blockIdx.x;
  const int t = threadIdx.x;
  const float4 v = ((const float4*)(res + (size_t)row * H_))[t];
  float s1 = v.x + v.y + v.z + v.w;
  float s2 = v.x*v.x + v.y*v.y + v.z*v.z + v.w*v.w;
  block_reduce2(s1, s2);
  if (t == 0) {
    const float m = s1 * (1.f / H_);
    const float var = s2 * (1.f / H_) - m * m;
    st[row] = make_float2(m, rsqrtf(var + 1e-5f));
  }
}

// ---------------- tiny converters (run once, off critical path) ----------------
__global__ __launch_bounds__(256) void tobf16_kernel(
    const float* __restrict__ s, unsigned short* __restrict__ d)
{
  const int i = blockIdx.x * 256 + threadIdx.x;
  const float4 v = ((const float4*)s)[i];
  uint2 p;
  p.x = pack_bf16(v.x, v.y); p.y = pack_bf16(v.z, v.w);
  ((uint2*)d)[i] = p;
}

__global__ __launch_bounds__(256) void splitw_kernel(
    const float* __restrict__ s, unsigned short* __restrict__ dh, unsigned short* __restrict__ dl)
{
  const int i = blockIdx.x * 256 + threadIdx.x;
  const float4 v = ((const float4*)s)[i];
  const float sv[4] = {v.x, v.y, v.z, v.w};
  unsigned h[4]; float l[4];
#pragma unroll
  for (int e = 0; e < 4; ++e) {
    h[e] = (__float_as_uint(sv[e]) + 0x8000u) & 0xFFFF0000u;
    l[e] = sv[e] - __uint_as_float(h[e]);
  }
  uint2 ph, pl;
  ph.x = pack_hi16(h[0], h[1]); ph.y = pack_hi16(h[2], h[3]);
  pl.x = pack_bf16(l[0], l[1]); pl.y = pack_bf16(l[2], l[3]);
  ((uint2*)dh)[i] = ph;
  ((uint2*)dl)[i] = pl;
}

// ---------------- bf16-input MFMA GEMM: C[M,N] = A[M,1024] @ W[N,1024]^T (A,W bf16) ----------------
__global__ __launch_bounds__(256) void gemm_bb(
    const unsigned short* __restrict__ A, const unsigned short* __restrict__ W,
    float* __restrict__ C)
{
  __shared__ __align__(16) unsigned short As[128 * 40];
  __shared__ __align__(16) unsigned short Ws[128 * 40];
  const int tid  = threadIdx.x;
  const int bn   = blockIdx.x & 7;
  const int bm   = blockIdx.x >> 3;
  const int wave = tid >> 6, lane = tid & 63;
  const int wm = (wave >> 1) * 64, wn = (wave & 1) * 64;
  const int fm = lane & 15, quad = lane >> 4;

  floatx4 acc[4][4];
#pragma unroll
  for (int i = 0; i < 4; ++i)
#pragma unroll
    for (int j = 0; j < 4; ++j) acc[i][j] = (floatx4){0.f, 0.f, 0.f, 0.f};

  const unsigned short* Abase = A + (size_t)bm * 128 * 1024;
  const unsigned short* Wbase = W + (size_t)bn * 128 * 1024;

  for (int k0 = 0; k0 < 1024; k0 += 32) {
    uint2 a2[4], w2[4];
#pragma unroll
    for (int i = 0; i < 4; ++i) {
      const int q = tid + 256 * i;
      const int row = q >> 3, ch = q & 7;
      a2[i] = *(const uint2*)(Abase + (size_t)row * 1024 + k0 + ch * 4);
      w2[i] = *(const uint2*)(Wbase + (size_t)row * 1024 + k0 + ch * 4);
    }
#pragma unroll
    for (int i = 0; i < 4; ++i) {
      const int q = tid + 256 * i;
      const int row = q >> 3, ch = q & 7;
      *(uint2*)(&As[row * 40 + ch * 4]) = a2[i];
      *(uint2*)(&Ws[row * 40 + ch * 4]) = w2[i];
    }
    __syncthreads();
    short8 af[4], wf[4];
#pragma unroll
    for (int i = 0; i < 4; ++i) {
      af[i] = *(const short8*)(&As[(wm + i * 16 + fm) * 40 + quad * 8]);
      wf[i] = *(const short8*)(&Ws[(wn + i * 16 + fm) * 40 + quad * 8]);
    }
#pragma unroll
    for (int i = 0; i < 4; ++i)
#pragma unroll
      for (int j = 0; j < 4; ++j)
        acc[i][j] = __builtin_amdgcn_mfma_f32_16x16x32_bf16(af[i], wf[j], acc[i][j], 0, 0, 0);
    __syncthreads();
  }

  // epilogue: C/D layout col=lane&15, row=quad*4+reg (m89/m91)
#pragma unroll
  for (int i = 0; i < 4; ++i) {
    const int grow0 = bm * 128 + wm + i * 16 + quad * 4;
#pragma unroll
    for (int j = 0; j < 4; ++j) {
      const int gcol = bn * 128 + wn + j * 16 + fm;
#pragma unroll
      for (int r = 0; r < 4; ++r)
        C[(size_t)(grow0 + r) * 1024 + gcol] = acc[i][j][r];
    }
  }
}

// ---------------- readout GEMM, MFMA hi/lo version (W pre-split into bf16 hi/lo) ----------------
// out[gr,e] = blend(gelu(LN(res)[gr,:] . ro_w[e,:] + bias[e]), ssm_recon, gate)
// A*W ~= Ah*Wh + Al*Wh + Ah*Wl (dropped Al*Wl ~2^-17). LN fused into A-staging.
__global__ __launch_bounds__(256) void gemm_readout_mfma(
    const float* __restrict__ A,      // reservoir states [M,1024]
    const unsigned short* __restrict__ Wh_g,  // bf16 hi of ro_w
    const unsigned short* __restrict__ Wl_g,  // bf16 lo of ro_w
    const float* __restrict__ bias,   // ro_bias
    const float2* __restrict__ lnst,  // per-row mean/rstd
    const float* __restrict__ lng, const float* __restrict__ lnb,
    const float* __restrict__ Avec,   // A[h]
    const float* __restrict__ cumd,   // within-chunk cumulative delta [M]
    const float* __restrict__ chH,    // per-chunk initial ssm state [B,16,1024]
    const float* __restrict__ gate,   // [M,1024]
    float* __restrict__ C)            // d_out: in = ssm local states, out = final
{
  __shared__ __align__(16) unsigned short Ah[128 * 40];
  __shared__ __align__(16) unsigned short Al[128 * 40];
  __shared__ __align__(16) unsigned short Wh[128 * 40];
  __shared__ __align__(16) unsigned short Wl[128 * 40];
  const int tid  = threadIdx.x;
  const int bn   = blockIdx.x & 7;
  const int bm   = blockIdx.x >> 3;
  const int wave = tid >> 6, lane = tid & 63;
  const int wm = (wave >> 1) * 64, wn = (wave & 1) * 64;
  const int fm = lane & 15, quad = lane >> 4;

  floatx4 acc[4][4];
#pragma unroll
  for (int i = 0; i < 4; ++i)
#pragma unroll
    for (int j = 0; j < 4; ++j) acc[i][j] = (floatx4){0.f, 0.f, 0.f, 0.f};

  const float* Abase = A + (size_t)bm * 128 * 1024;
  const unsigned short* Whb = Wh_g + (size_t)bn * 128 * 1024;
  const unsigned short* Wlb = Wl_g + (size_t)bn * 128 * 1024;

  // per-thread staged-row stats (row fixed per i across k-tiles)
  float2 st_i[4];
#pragma unroll
  for (int i = 0; i < 4; ++i) {
    const int q = tid + 256 * i;
    st_i[i] = lnst[bm * 128 + (q >> 3)];
  }

  for (int k0 = 0; k0 < 1024; k0 += 32) {
#pragma unroll
    for (int i = 0; i < 4; ++i) {
      const int q = tid + 256 * i;
      const int row = q >> 3, ch = q & 7;
      float4 a4 = *(const float4*)(Abase + (size_t)row * 1024 + k0 + ch * 4);
      const float4 g4 = *(const float4*)(lng + k0 + ch * 4);
      const float4 b4 = *(const float4*)(lnb + k0 + ch * 4);
      const float2 st = st_i[i];
      a4.x = (a4.x - st.x) * st.y * g4.x + b4.x;
      a4.y = (a4.y - st.x) * st.y * g4.y + b4.y;
      a4.z = (a4.z - st.x) * st.y * g4.z + b4.z;
      a4.w = (a4.w - st.x) * st.y * g4.w + b4.w;
      // hi/lo split of A
      const float av[4] = {a4.x, a4.y, a4.z, a4.w};
      unsigned ah[4]; float alr[4];
#pragma unroll
      for (int e = 0; e < 4; ++e) {
        ah[e] = (__float_as_uint(av[e]) + 0x8000u) & 0xFFFF0000u;
        alr[e] = av[e] - __uint_as_float(ah[e]);
      }
      uint2 pah, pal;
      pah.x = pack_hi16(ah[0], ah[1]); pah.y = pack_hi16(ah[2], ah[3]);
      pal.x = pack_bf16(alr[0], alr[1]); pal.y = pack_bf16(alr[2], alr[3]);
      *(uint2*)(&Ah[row * 40 + ch * 4]) = pah;
      *(uint2*)(&Al[row * 40 + ch * 4]) = pal;
      // W: pre-split, plain copies
      *(uint2*)(&Wh[row * 40 + ch * 4]) = *(const uint2*)(Whb + (size_t)row * 1024 + k0 + ch * 4);
      *(uint2*)(&Wl[row * 40 + ch * 4]) = *(const uint2*)(Wlb + (size_t)row * 1024 + k0 + ch * 4);
    }
    __syncthreads();
    short8 afh[4], afl[4], wfh[4], wfl[4];
#pragma unroll
    for (int i = 0; i < 4; ++i) {
      const int ao = (wm + i * 16 + fm) * 40 + quad * 8;
      const int wo = (wn + i * 16 + fm) * 40 + quad * 8;
      afh[i] = *(const short8*)(&Ah[ao]);
      afl[i] = *(const short8*)(&Al[ao]);
      wfh[i] = *(const short8*)(&Wh[wo]);
      wfl[i] = *(const short8*)(&Wl[wo]);
    }
#pragma unroll
    for (int i = 0; i < 4; ++i)
#pragma unroll
      for (int j = 0; j < 4; ++j) {
        acc[i][j] = __builtin_amdgcn_mfma_f32_16x16x32_bf16(afh[i], wfh[j], acc[i][j], 0, 0, 0);
        acc[i][j] = __builtin_amdgcn_mfma_f32_16x16x32_bf16(afl[i], wfh[j], acc[i][j], 0, 0, 0);
        acc[i][j] = __builtin_amdgcn_mfma_f32_16x16x32_bf16(afh[i], wfl[j], acc[i][j], 0, 0, 0);
      }
    __syncthreads();
  }

  // epilogue: C/D layout col=lane&15, row=quad*4+reg; gelu + ssm recon + gate blend
#pragma unroll
  for (int i = 0; i < 4; ++i) {
    const int grow0 = bm * 128 + wm + i * 16 + quad * 4;
    float cd_r[4];
    int hb_r[4];
#pragma unroll
    for (int r = 0; r < 4; ++r) {
      const int gr = grow0 + r;
      const int b = gr >> 11;           // gr = b*2048 + s
      const int c = (gr & 2047) >> 7;   // 128-step chunk
      cd_r[r] = cumd[gr];
      hb_r[r] = (b * 16 + c) << 10;
    }
#pragma unroll
    for (int j = 0; j < 4; ++j) {
      const int gcol = bn * 128 + wn + j * 16 + fm;
      const float Ae = Avec[gcol];
      const float bb = bias[gcol];
#pragma unroll
      for (int r = 0; r < 4; ++r) {
        const int gr = grow0 + r;
        const size_t off = (size_t)gr * 1024 + gcol;
        const float hin = chH[hb_r[r] + gcol];
        const float lcl = C[off];
        const float gt  = gate[off];
        float v = acc[i][j][r] + bb;
        v = 0.5f * v * (1.f + erff(v * 0.70710678118654752f));   // exact gelu
        const float p = __expf(Ae * cd_r[r]);                    // prod of A_bar over chunk prefix
        const float sst = lcl + p * hin;                         // true ssm state
        C[off] = v * gt + sst * (1.f - gt);
      }
    }
  }
}

// ---------------- fused scan + gate kernel ----------------
// WGs 0..127: reservoir scan, EXACTLY the round-9 structure (batch-partitioned groups of 16,
//   one-word poll, WG-shared swizzled LDS staging, single barrier, butterfly reduce, coalesced
//   tail). Counters showed it latency/skew-bound with ~128 CUs idle -> fill them:
// WGs 128..1151: gate = sigmoid(x @ gate_w^T + gate_b) tiles (the proven gemm_bf16_nt<1> body,
//   256 active threads; threads 256..511 participate in barriers only). Gate depends only on
//   inputs and is consumed only by the readout -> safe to run concurrently with the scan.
// Deadlock-safety: gate WGs never spin (finite work); scan WGs spin only on other scan WGs.
// Queued scan WGs eventually launch as gate WGs retire -> progress guaranteed regardless of
// dispatch order (worst case = lost overlap, not deadlock).
// Scan safety invariants unchanged from round 9 (per-group: tag store post-dates barrier which
// post-dates all polls; parity overwrite certified by poll success; LDS dbuf separated by
// barrier). Gate WGs touch only x/gate_w/gate_b/out-gate — disjoint from scan state.
__global__ __launch_bounds__(512, 2) void scan_gate_kernel(
    float* __restrict__ xin_res,       // [8][2048][1024]: in xin, out res states (in-place)
    const float* __restrict__ Wres,    // [1024][1024]
    unsigned* __restrict__ hbuf,       // [2][8][1024] packed words, zeroed before launch
    const float* __restrict__ x,       // input x [M,1024]
    const float* __restrict__ gate_w,  // [1024,1024]
    const float* __restrict__ gate_b,  // [1024]
    float* __restrict__ gateout)       // [M,1024]
{
  __shared__ __align__(16) unsigned char smem[20480];   // scan: 8KB hs dbuf / gate: 20KB As|Ws
  const int wg  = blockIdx.x;
  const int tid = threadIdx.x;

  if (wg < 128) {
    // ================= scan path (round-9, verbatim logic) =================
    float* hsb = (float*)smem;           // [2][1024]
    const int go  = wg >> 4;             // batch group 0..7
    const int mem = wg & 15;             // member: rows mem*64..mem*64+63
    const int g   = tid >> 6;            // wave 0..7
    const int l   = tid & 63;
    const int row8 = mem * 64 + g * 8;   // wave's 8-row base

    // W registers: 8 rows x 16 k per thread (k = 16l .. 16l+15)
    float4 w4[8][4];
#pragma unroll
    for (int r = 0; r < 8; ++r) {
      const float* wrow = Wres + (size_t)(row8 + r) * 1024 + l * 16;
#pragma unroll
      for (int j = 0; j < 4; ++j) w4[r][j] = *(const float4*)(wrow + 4 * j);
    }

    const int m0 = l & 1, m1 = (l >> 1) & 1, m2 = (l >> 2) & 1;
    const int myrow = row8 + (l & 7);    // row this lane finalizes (lanes 8+ duplicate)
    float hprev = 0.f;
    const unsigned long long tmask = 0x0000FFFF0000FFFFull;

    // staging: thread writes floats (2*tid, 2*tid+1) -> logical line Lw=tid>>1, swizzled
    const int Pw = (tid >> 1) ^ ((tid >> 6) & 7);
    const int wofs = Pw * 4 + (tid & 1) * 2;

    for (int s = 0; s < S_; ++s) {
      // prefetch u before the poll (keep-alive pins issue order)
      const float u = xin_res[((size_t)go * S_ + s) * H_ + myrow];
      asm volatile("" :: "v"(u));

      // poll h^s: ONE u64 per thread (rows 2*tid, 2*tid+1 of this group)
      const unsigned tag = (unsigned)s & 0xFFFFu;
      const unsigned long long tag2 = (unsigned long long)tag | ((unsigned long long)tag << 32);
      const unsigned long long* hp =
          (const unsigned long long*)(hbuf + (size_t)(s & 1) * 8192 + go * 1024) + tid;
      unsigned long long w;
      for (;;) {
        w = __hip_atomic_load(hp, __ATOMIC_RELAXED, __HIP_MEMORY_SCOPE_AGENT);
        if (((w ^ tag2) & tmask) == 0ull) break;
      }

      // stage as fp32 (mask off tag), one ds_write_b64 to swizzled line
      float2 hf;
      hf.x = __uint_as_float((unsigned)w & 0xFFFF0000u);
      hf.y = __uint_as_float((unsigned)(w >> 32) & 0xFFFF0000u);
      *(float2*)(hsb + (s & 1) * 1024 + wofs) = hf;
      __syncthreads();                   // the only barrier: staged; all polls done before
                                         // any tag-s+1 store below (safety inv.)

      // matvec: 8 rows x 16 k per thread; 4 wide ds_read_b128 (distinct line/lane)
      const float* hbse = hsb + (s & 1) * 1024;
      float acc0 = 0.f, acc1 = 0.f, acc2 = 0.f, acc3 = 0.f;
      float acc4 = 0.f, acc5 = 0.f, acc6 = 0.f, acc7 = 0.f;
#pragma unroll
      for (int j = 0; j < 4; ++j) {
        const int P = (4 * l + j) ^ ((l >> 3) & 7);
        const float4 h4 = *(const float4*)(hbse + P * 4);
        acc0 += w4[0][j].x * h4.x + w4[0][j].y * h4.y + w4[0][j].z * h4.z + w4[0][j].w * h4.w;
        acc1 += w4[1][j].x * h4.x + w4[1][j].y * h4.y + w4[1][j].z * h4.z + w4[1][j].w * h4.w;
        acc2 += w4[2][j].x * h4.x + w4[2][j].y * h4.y + w4[2][j].z * h4.z + w4[2][j].w * h4.w;
        acc3 += w4[3][j].x * h4.x + w4[3][j].y * h4.y + w4[3][j].z * h4.z + w4[3][j].w * h4.w;
        acc4 += w4[4][j].x * h4.x + w4[4][j].y * h4.y + w4[4][j].z * h4.z + w4[4][j].w * h4.w;
        acc5 += w4[5][j].x * h4.x + w4[5][j].y * h4.y + w4[5][j].z * h4.z + w4[5][j].w * h4.w;
        acc6 += w4[6][j].x * h4.x + w4[6][j].y * h4.y + w4[6][j].z * h4.z + w4[6][j].w * h4.w;
        acc7 += w4[7][j].x * h4.x + w4[7][j].y * h4.y + w4[7][j].z * h4.z + w4[7][j].w * h4.w;
      }

      // butterfly reduce-scatter: rows onto lane bits 0..2, then tree over bits 3..5
      float v0 = (m0 ? acc1 : acc0) + __shfl_xor(m0 ? acc0 : acc1, 1);
      float v1 = (m0 ? acc3 : acc2) + __shfl_xor(m0 ? acc2 : acc3, 1);
      float v2 = (m0 ? acc5 : acc4) + __shfl_xor(m0 ? acc4 : acc5, 1);
      float v3 = (m0 ? acc7 : acc6) + __shfl_xor(m0 ? acc6 : acc7, 1);
      float u0 = (m1 ? v1 : v0) + __shfl_xor(m1 ? v0 : v1, 2);
      float u1 = (m1 ? v3 : v2) + __shfl_xor(m1 ? v2 : v3, 2);
      float ps = (m2 ? u1 : u0) + __shfl_xor(m2 ? u0 : u1, 4);
      ps += __shfl_xor(ps, 8);
      ps += __shfl_xor(ps, 16);
      ps += __shfl_xor(ps, 32);

      // tanh, leak (all lanes; duplicates consistent), lanes 0..7 store
      const float z  = u + ps;
      const float e  = __expf(2.f * z);                 // tanh(z) = 1 - 2/(e^{2z}+1)
      const float hn = 1.f - __fdividef(2.f, e + 1.f);  // saturates correctly
      const float hv = 0.95f * hn + 0.05f * hprev;
      hprev = hv;

      if (l < 8) {
        const unsigned word = ((__float_as_uint(hv) + 0x8000u) & 0xFFFF0000u)
                            | ((unsigned)(s + 1) & 0xFFFFu);
        __hip_atomic_store(hbuf + (size_t)((s + 1) & 1) * 8192 + go * 1024 + myrow, word,
                           __ATOMIC_RELAXED, __HIP_MEMORY_SCOPE_AGENT);
        xin_res[((size_t)go * S_ + s) * H_ + myrow] = hv;  // fp32 states, 32B-dense per wave
      }
      // no drain, no flag, no rendezvous — next iteration's poll is the wait
    }
  } else {
    // ================= gate path: sigmoid(x @ gate_w^T + gate_b) tile =================
    unsigned short* As = (unsigned short*)smem;            // [128*40]
    unsigned short* Ws = As + 128 * 40;                    // [128*40]
    const int bidx = wg - 128;           // 0..1023
    const int bn   = bidx & 7;
    const int bm   = bidx >> 3;
    const bool act = tid < 256;
    const int wave = tid >> 6, lane = tid & 63;            // waves 0..3 active
    const int wm = (wave >> 1) * 64, wn = (wave & 1) * 64;
    const int fm = lane & 15, quad = lane >> 4;

    floatx4 acc[4][4];
#pragma unroll
    for (int i = 0; i < 4; ++i)
#pragma unroll
      for (int j = 0; j < 4; ++j) acc[i][j] = (floatx4){0.f, 0.f, 0.f, 0.f};

    const float* Abase = x + (size_t)bm * 128 * 1024;
    const float* Wbase = gate_w + (size_t)bn * 128 * 1024;

    for (int k0 = 0; k0 < 1024; k0 += 32) {
      if (act) {
        float4 a4[4], w4g[4];
#pragma unroll
        for (int i = 0; i < 4; ++i) {
          const int q = tid + 256 * i;
          const int row = q >> 3, ch = q & 7;
          a4[i]  = *(const float4*)(Abase + (size_t)row * 1024 + k0 + ch * 4);
          w4g[i] = *(const float4*)(Wbase + (size_t)row * 1024 + k0 + ch * 4);
        }
#pragma unroll
        for (int i = 0; i < 4; ++i) {
          const int q = tid + 256 * i;
          const int row = q >> 3, ch = q & 7;
          uint2 pa, pw;
          pa.x = pack_bf16(a4[i].x, a4[i].y);  pa.y = pack_bf16(a4[i].z, a4[i].w);
          pw.x = pack_bf16(w4g[i].x, w4g[i].y); pw.y = pack_bf16(w4g[i].z, w4g[i].w);
          *(uint2*)(&As[row * 40 + ch * 4]) = pa;
          *(uint2*)(&Ws[row * 40 + ch * 4]) = pw;
        }
      }
      __syncthreads();
      if (act) {
        short8 af[4], wf[4];
#pragma unroll
        for (int i = 0; i < 4; ++i) {
          af[i] = *(const short8*)(&As[(wm + i * 16 + fm) * 40 + quad * 8]);
          wf[i] = *(const short8*)(&Ws[(wn + i * 16 + fm) * 40 + quad * 8]);
        }
#pragma unroll
        for (int i = 0; i < 4; ++i)
#pragma unroll
          for (int j = 0; j < 4; ++j)
            acc[i][j] = __builtin_amdgcn_mfma_f32_16x16x32_bf16(af[i], wf[j], acc[i][j], 0, 0, 0);
      }
      __syncthreads();
    }

    if (act) {
      // epilogue: C/D layout col=lane&15, row=quad*4+reg; sigmoid
#pragma unroll
      for (int i = 0; i < 4; ++i) {
        const int grow0 = bm * 128 + wm + i * 16 + quad * 4;
#pragma unroll
        for (int j = 0; j < 4; ++j) {
          const int gcol = bn * 128 + wn + j * 16 + fm;
          const float bb = gate_b[gcol];
#pragma unroll
          for (int r = 0; r < 4; ++r) {
            float v = acc[i][j][r] + bb;
            v = 1.f / (1.f + __expf(-v));
            gateout[(size_t)(grow0 + r) * 1024 + gcol] = v;
          }
        }
      }
    }
  }
}

// ---------------- SSM chunked scan ----------------
// within-chunk cumulative delta (tiny)
__global__ __launch_bounds__(128) void cumd_kernel(
    const float* __restrict__ delta, float* __restrict__ cumd)
{
  const int t = threadIdx.x;          // 128 = 8 batches * 16 chunks
  const int b = t >> 4, c = t & 15;
  const int base = b * S_ + c * 128;
  float acc = 0.f;
  for (int i = 0; i < 128; ++i) { acc += delta[base + i]; cumd[base + i] = acc; }
}

// phase A: per-chunk local scan, in-place Bx -> local states; store chunk products
__global__ __launch_bounds__(256) void ssm_partial_kernel(
    const float* __restrict__ delta, const float* __restrict__ Avec,
    float* __restrict__ bx, float* __restrict__ P)
{
  const int idx = blockIdx.x * 256 + threadIdx.x;
  const int h = idx & 1023;
  const int c = (idx >> 10) & 15;
  const int b = idx >> 14;
  const float Ah = Avec[h];
  const float inv = 1.f / (Ah + 1e-8f);
  const float* dp = delta + b * S_ + c * 128;
  float* xp = bx + ((size_t)(b * S_ + c * 128)) * H_ + h;
  float p = 1.f, hl = 0.f;
  for (int t = 0; t < 128; ++t) {
    const float a = __expf(Ah * dp[t]);
    const float bb = xp[(size_t)t * H_] * (1.f - a) * inv;
    hl = a * hl + bb;
    p *= a;
    xp[(size_t)t * H_] = hl;
  }
  P[(b * 16 + c) * 1024 + h] = p;
}

// phase B: sequential combine over 16 chunks -> per-chunk initial states
__global__ __launch_bounds__(256) void ssm_combine_kernel(
    const float* __restrict__ P, const float* __restrict__ local, float* __restrict__ Hin)
{
  const int idx = blockIdx.x * 256 + threadIdx.x;  // 8192
  const int h = idx & 1023;
  const int b = idx >> 10;
  float hh = 0.f;
#pragma unroll
  for (int c = 0; c < 16; ++c) {
    const int o = (b * 16 + c) * 1024 + h;
    Hin[o] = hh;
    hh = P[o] * hh + local[((size_t)(b * S_ + c * 128 + 127)) * H_ + h];
  }
}

// ---------------- host launch ----------------
extern "C" void kernel_launch(void* const* d_in, const int* in_sizes, int n_in,
                              void* d_out, int out_size, void* d_ws, size_t ws_size,
                              hipStream_t stream) {
  (void)in_sizes; (void)n_in; (void)out_size; (void)ws_size;
  const float* x      = (const float*)d_in[0];
  const float* W_in   = (const float*)d_in[1];
  const float* W_res  = (const float*)d_in[2];
  const float* norm_g = (const float*)d_in[3];
  const float* norm_b = (const float*)d_in[4];
  const float* dw     = (const float*)d_in[5];
  const float* db     = (const float*)d_in[6];
  const float* Avec   = (const float*)d_in[7];
  const float* B_w    = (const float*)d_in[8];
  const float* ro_g   = (const float*)d_in[9];
  const float* ro_b   = (const float*)d_in[10];
  const float* ro_w   = (const float*)d_in[11];
  const float* ro_bias= (const float*)d_in[12];
  const float* gate_w = (const float*)d_in[13];
  const float* gate_b = (const float*)d_in[14];
  float* out = (float*)d_out;
  float* ws  = (float*)d_ws;

  float*    buf0   = ws;                    // bf16 x_norm (first 32MB), later fp32 gate (64MB)
  float*    buf1   = ws + 16777216;         // xin -> reservoir states (in-place)
  float*    delta  = ws + 33554432;         // [M]
  float*    cumd   = ws + 33570816;         // [M]
  unsigned* hbuf   = (unsigned*)(ws + 33587200);  // [2][8][1024] packed words
  float2*   stats  = (float2*)(ws + 33603712);
  float*    chP    = ws + 33636480;         // [B,16,1024]
  float*    chH    = ws + 33767552;         // [B,16,1024]
  unsigned short* xnb = (unsigned short*)buf0;            // bf16 x_norm [M,1024]
  unsigned short* wib = (unsigned short*)(ws + 33898624); // bf16 W_in   [1024,1024]
  unsigned short* bwb = (unsigned short*)(ws + 34422912); // bf16 B_w
  unsigned short* roh = (unsigned short*)(ws + 34947200); // bf16 hi(ro_w)
  unsigned short* rol = (unsigned short*)(ws + 35471488); // bf16 lo(ro_w)

  // 0. weight conversions (once per launch, tiny)
  tobf16_kernel<<<1024, 256, 0, stream>>>(W_in, wib);
  tobf16_kernel<<<1024, 256, 0, stream>>>(B_w, bwb);
  splitw_kernel<<<1024, 256, 0, stream>>>(ro_w, roh, rol);
  // 1. layernorm -> bf16 x_norm + delta
  ln_delta_kernel<<<M_, 256, 0, stream>>>(x, norm_g, norm_b, dw, db, xnb, delta);
  // 2. xin = x_norm @ W_in^T   -> buf1   (bf16 x bf16 MFMA)
  gemm_bb<<<1024, 256, 0, stream>>>(xnb, wib, buf1);
  // 3. Bx = x_norm @ B_w^T     -> d_out (scratch)
  gemm_bb<<<1024, 256, 0, stream>>>(xnb, bwb, out);
  // 4. ssm chunked scan pieces (independent of reservoir)
  cumd_kernel<<<1, 128, 0, stream>>>(delta, cumd);
  ssm_partial_kernel<<<512, 256, 0, stream>>>(delta, Avec, out, chP);
  ssm_combine_kernel<<<32, 256, 0, stream>>>(chP, out, chH);
  // 5. fused: reservoir scan (WGs 0..127) + gate GEMM (WGs 128..1151, -> buf0; xnb dead)
  hipMemsetAsync(hbuf, 0, 2 * 8192 * sizeof(unsigned), stream);
  scan_gate_kernel<<<1152, 512, 0, stream>>>(buf1, W_res, hbuf, x, gate_w, gate_b, buf0);
  // 6. ro-layernorm stats
  rowstats_kernel<<<M_, 256, 0, stream>>>(buf1, stats);
  // 7. readout GEMM (MFMA hi/lo, pre-split W) + gelu + ssm recon + gate blend -> d_out
  gemm_readout_mfma<<<1024, 256, 0, stream>>>(buf1, roh, rol, ro_bias, stats, ro_g, ro_b,
                                              Avec, cumd, chH, buf0, out);
}

// Round 11
// 3442.079 us; speedup vs baseline: 1.3101x; 1.1180x over previous
//
#include <hip/hip_runtime.h>
#include <math.h>

#define B_ 8
#define S_ 2048
#define E_ 1024
#define H_ 1024
#define M_ 16384   // B_*S_

typedef __attribute__((ext_vector_type(8))) short short8;    // 8 bf16 = 4 VGPRs
typedef __attribute__((ext_vector_type(4))) float floatx4;

// ---------------- block-wide reduction of two floats (256 threads = 4 waves) ----------------
__device__ __forceinline__ void block_reduce2(float &a, float &b) {
#pragma unroll
  for (int off = 32; off > 0; off >>= 1) {
    a += __shfl_down(a, off);
    b += __shfl_down(b, off);
  }
  __shared__ float sa[4], sb[4];
  const int w = threadIdx.x >> 6;
  __syncthreads();                 // protects reuse across back-to-back calls
  if ((threadIdx.x & 63) == 0) { sa[w] = a; sb[w] = b; }
  __syncthreads();
  a = sa[0] + sa[1] + sa[2] + sa[3];
  b = sb[0] + sb[1] + sb[2] + sb[3];
}

__device__ __forceinline__ unsigned pack_bf16(float lo, float hi) {
  return __builtin_amdgcn_perm(__float_as_uint(hi) + 0x8000u,
                               __float_as_uint(lo) + 0x8000u, 0x07060302u);
}
// pack the hi16 of two u32 bit patterns: (hi16(a) in low half, hi16(b) in high half)
__device__ __forceinline__ unsigned pack_hi16(unsigned a, unsigned b) {
  return __builtin_amdgcn_perm(b, a, 0x07060302u);
}

// ---------------- LayerNorm(x) -> x_norm (bf16!), plus delta = softplus(x_norm . delta_w + db) ----------------
__global__ __launch_bounds__(256) void ln_delta_kernel(
    const float* __restrict__ x, const float* __restrict__ g, const float* __restrict__ bt,
    const float* __restrict__ dw, const float* __restrict__ db,
    unsigned short* __restrict__ xnb, float* __restrict__ delta)
{
  const int row = blockIdx.x;
  const int t = threadIdx.x;
  const float4 v = ((const float4*)(x + (size_t)row * E_))[t];
  float s1 = v.x + v.y + v.z + v.w;
  float s2 = v.x*v.x + v.y*v.y + v.z*v.z + v.w*v.w;
  block_reduce2(s1, s2);
  const float mean = s1 * (1.f / E_);
  const float var  = s2 * (1.f / E_) - mean * mean;
  const float rstd = rsqrtf(var + 1e-5f);
  const float4 g4 = ((const float4*)g)[t];
  const float4 b4 = ((const float4*)bt)[t];
  float4 o;
  o.x = (v.x - mean) * rstd * g4.x + b4.x;
  o.y = (v.y - mean) * rstd * g4.y + b4.y;
  o.z = (v.z - mean) * rstd * g4.z + b4.z;
  o.w = (v.w - mean) * rstd * g4.w + b4.w;
  uint2 p;
  p.x = pack_bf16(o.x, o.y); p.y = pack_bf16(o.z, o.w);
  ((uint2*)(xnb + (size_t)row * E_))[t] = p;       // bf16 x_norm (same rounding the GEMMs used)
  const float4 d4 = ((const float4*)dw)[t];
  float dd = o.x*d4.x + o.y*d4.y + o.z*d4.z + o.w*d4.w;   // delta stays fp32-accurate
  float dummy = 0.f;
  block_reduce2(dd, dummy);
  if (t == 0) {
    const float z = dd + db[0];
    delta[row] = (z > 20.f) ? z : log1pf(__expf(z));
  }
}

// ---------------- per-row mean/rstd of reservoir states (for fused ro-layernorm) ----------------
__global__ __launch_bounds__(256) void rowstats_kernel(
    const float* __restrict__ res, float2* __restrict__ st)
{
  const int row = blockIdx.x;
  const int t = threadIdx.x;
  const float4 v = ((const float4*)(res + (size_t)row * H_))[t];
  float s1 = v.x + v.y + v.z + v.w;
  float s2 = v.x*v.x + v.y*v.y + v.z*v.z + v.w*v.w;
  block_reduce2(s1, s2);
  if (t == 0) {
    const float m = s1 * (1.f / H_);
    const float var = s2 * (1.f / H_) - m * m;
    st[row] = make_float2(m, rsqrtf(var + 1e-5f));
  }
}

// ---------------- tiny converters (run once, off critical path) ----------------
__global__ __launch_bounds__(256) void tobf16_kernel(
    const float* __restrict__ s, unsigned short* __restrict__ d)
{
  const int i = blockIdx.x * 256 + threadIdx.x;
  const float4 v = ((const float4*)s)[i];
  uint2 p;
  p.x = pack_bf16(v.x, v.y); p.y = pack_bf16(v.z, v.w);
  ((uint2*)d)[i] = p;
}

__global__ __launch_bounds__(256) void splitw_kernel(
    const float* __restrict__ s, unsigned short* __restrict__ dh, unsigned short* __restrict__ dl)
{
  const int i = blockIdx.x * 256 + threadIdx.x;
  const float4 v = ((const float4*)s)[i];
  const float sv[4] = {v.x, v.y, v.z, v.w};
  unsigned h[4]; float l[4];
#pragma unroll
  for (int e = 0; e < 4; ++e) {
    h[e] = (__float_as_uint(sv[e]) + 0x8000u) & 0xFFFF0000u;
    l[e] = sv[e] - __uint_as_float(h[e]);
  }
  uint2 ph, pl;
  ph.x = pack_hi16(h[0], h[1]); ph.y = pack_hi16(h[2], h[3]);
  pl.x = pack_bf16(l[0], l[1]); pl.y = pack_bf16(l[2], l[3]);
  ((uint2*)dh)[i] = ph;
  ((uint2*)dl)[i] = pl;
}

// ---------------- bf16-input MFMA GEMM: C[M,N] = A[M,1024] @ W[N,1024]^T (A,W bf16) ----------------
__global__ __launch_bounds__(256) void gemm_bb(
    const unsigned short* __restrict__ A, const unsigned short* __restrict__ W,
    float* __restrict__ C)
{
  __shared__ __align__(16) unsigned short As[128 * 40];
  __shared__ __align__(16) unsigned short Ws[128 * 40];
  const int tid  = threadIdx.x;
  const int bn   = blockIdx.x & 7;
  const int bm   = blockIdx.x >> 3;
  const int wave = tid >> 6, lane = tid & 63;
  const int wm = (wave >> 1) * 64, wn = (wave & 1) * 64;
  const int fm = lane & 15, quad = lane >> 4;

  floatx4 acc[4][4];
#pragma unroll
  for (int i = 0; i < 4; ++i)
#pragma unroll
    for (int j = 0; j < 4; ++j) acc[i][j] = (floatx4){0.f, 0.f, 0.f, 0.f};

  const unsigned short* Abase = A + (size_t)bm * 128 * 1024;
  const unsigned short* Wbase = W + (size_t)bn * 128 * 1024;

  for (int k0 = 0; k0 < 1024; k0 += 32) {
    uint2 a2[4], w2[4];
#pragma unroll
    for (int i = 0; i < 4; ++i) {
      const int q = tid + 256 * i;
      const int row = q >> 3, ch = q & 7;
      a2[i] = *(const uint2*)(Abase + (size_t)row * 1024 + k0 + ch * 4);
      w2[i] = *(const uint2*)(Wbase + (size_t)row * 1024 + k0 + ch * 4);
    }
#pragma unroll
    for (int i = 0; i < 4; ++i) {
      const int q = tid + 256 * i;
      const int row = q >> 3, ch = q & 7;
      *(uint2*)(&As[row * 40 + ch * 4]) = a2[i];
      *(uint2*)(&Ws[row * 40 + ch * 4]) = w2[i];
    }
    __syncthreads();
    short8 af[4], wf[4];
#pragma unroll
    for (int i = 0; i < 4; ++i) {
      af[i] = *(const short8*)(&As[(wm + i * 16 + fm) * 40 + quad * 8]);
      wf[i] = *(const short8*)(&Ws[(wn + i * 16 + fm) * 40 + quad * 8]);
    }
#pragma unroll
    for (int i = 0; i < 4; ++i)
#pragma unroll
      for (int j = 0; j < 4; ++j)
        acc[i][j] = __builtin_amdgcn_mfma_f32_16x16x32_bf16(af[i], wf[j], acc[i][j], 0, 0, 0);
    __syncthreads();
  }

  // epilogue: C/D layout col=lane&15, row=quad*4+reg (m89/m91)
#pragma unroll
  for (int i = 0; i < 4; ++i) {
    const int grow0 = bm * 128 + wm + i * 16 + quad * 4;
#pragma unroll
    for (int j = 0; j < 4; ++j) {
      const int gcol = bn * 128 + wn + j * 16 + fm;
#pragma unroll
      for (int r = 0; r < 4; ++r)
        C[(size_t)(grow0 + r) * 1024 + gcol] = acc[i][j][r];
    }
  }
}

// ---------------- readout GEMM, MFMA hi/lo version (W pre-split into bf16 hi/lo) ----------------
// out[gr,e] = blend(gelu(LN(res)[gr,:] . ro_w[e,:] + bias[e]), ssm_recon, gate)
// A*W ~= Ah*Wh + Al*Wh + Ah*Wl (dropped Al*Wl ~2^-17). LN fused into A-staging.
__global__ __launch_bounds__(256) void gemm_readout_mfma(
    const float* __restrict__ A,      // reservoir states [M,1024]
    const unsigned short* __restrict__ Wh_g,  // bf16 hi of ro_w
    const unsigned short* __restrict__ Wl_g,  // bf16 lo of ro_w
    const float* __restrict__ bias,   // ro_bias
    const float2* __restrict__ lnst,  // per-row mean/rstd
    const float* __restrict__ lng, const float* __restrict__ lnb,
    const float* __restrict__ Avec,   // A[h]
    const float* __restrict__ cumd,   // within-chunk cumulative delta [M]
    const float* __restrict__ chH,    // per-chunk initial ssm state [B,16,1024]
    const float* __restrict__ gate,   // [M,1024]
    float* __restrict__ C)            // d_out: in = ssm local states, out = final
{
  __shared__ __align__(16) unsigned short Ah[128 * 40];
  __shared__ __align__(16) unsigned short Al[128 * 40];
  __shared__ __align__(16) unsigned short Wh[128 * 40];
  __shared__ __align__(16) unsigned short Wl[128 * 40];
  const int tid  = threadIdx.x;
  const int bn   = blockIdx.x & 7;
  const int bm   = blockIdx.x >> 3;
  const int wave = tid >> 6, lane = tid & 63;
  const int wm = (wave >> 1) * 64, wn = (wave & 1) * 64;
  const int fm = lane & 15, quad = lane >> 4;

  floatx4 acc[4][4];
#pragma unroll
  for (int i = 0; i < 4; ++i)
#pragma unroll
    for (int j = 0; j < 4; ++j) acc[i][j] = (floatx4){0.f, 0.f, 0.f, 0.f};

  const float* Abase = A + (size_t)bm * 128 * 1024;
  const unsigned short* Whb = Wh_g + (size_t)bn * 128 * 1024;
  const unsigned short* Wlb = Wl_g + (size_t)bn * 128 * 1024;

  // per-thread staged-row stats (row fixed per i across k-tiles)
  float2 st_i[4];
#pragma unroll
  for (int i = 0; i < 4; ++i) {
    const int q = tid + 256 * i;
    st_i[i] = lnst[bm * 128 + (q >> 3)];
  }

  for (int k0 = 0; k0 < 1024; k0 += 32) {
#pragma unroll
    for (int i = 0; i < 4; ++i) {
      const int q = tid + 256 * i;
      const int row = q >> 3, ch = q & 7;
      float4 a4 = *(const float4*)(Abase + (size_t)row * 1024 + k0 + ch * 4);
      const float4 g4 = *(const float4*)(lng + k0 + ch * 4);
      const float4 b4 = *(const float4*)(lnb + k0 + ch * 4);
      const float2 st = st_i[i];
      a4.x = (a4.x - st.x) * st.y * g4.x + b4.x;
      a4.y = (a4.y - st.x) * st.y * g4.y + b4.y;
      a4.z = (a4.z - st.x) * st.y * g4.z + b4.z;
      a4.w = (a4.w - st.x) * st.y * g4.w + b4.w;
      // hi/lo split of A
      const float av[4] = {a4.x, a4.y, a4.z, a4.w};
      unsigned ah[4]; float alr[4];
#pragma unroll
      for (int e = 0; e < 4; ++e) {
        ah[e] = (__float_as_uint(av[e]) + 0x8000u) & 0xFFFF0000u;
        alr[e] = av[e] - __uint_as_float(ah[e]);
      }
      uint2 pah, pal;
      pah.x = pack_hi16(ah[0], ah[1]); pah.y = pack_hi16(ah[2], ah[3]);
      pal.x = pack_bf16(alr[0], alr[1]); pal.y = pack_bf16(alr[2], alr[3]);
      *(uint2*)(&Ah[row * 40 + ch * 4]) = pah;
      *(uint2*)(&Al[row * 40 + ch * 4]) = pal;
      // W: pre-split, plain copies
      *(uint2*)(&Wh[row * 40 + ch * 4]) = *(const uint2*)(Whb + (size_t)row * 1024 + k0 + ch * 4);
      *(uint2*)(&Wl[row * 40 + ch * 4]) = *(const uint2*)(Wlb + (size_t)row * 1024 + k0 + ch * 4);
    }
    __syncthreads();
    short8 afh[4], afl[4], wfh[4], wfl[4];
#pragma unroll
    for (int i = 0; i < 4; ++i) {
      const int ao = (wm + i * 16 + fm) * 40 + quad * 8;
      const int wo = (wn + i * 16 + fm) * 40 + quad * 8;
      afh[i] = *(const short8*)(&Ah[ao]);
      afl[i] = *(const short8*)(&Al[ao]);
      wfh[i] = *(const short8*)(&Wh[wo]);
      wfl[i] = *(const short8*)(&Wl[wo]);
    }
#pragma unroll
    for (int i = 0; i < 4; ++i)
#pragma unroll
      for (int j = 0; j < 4; ++j) {
        acc[i][j] = __builtin_amdgcn_mfma_f32_16x16x32_bf16(afh[i], wfh[j], acc[i][j], 0, 0, 0);
        acc[i][j] = __builtin_amdgcn_mfma_f32_16x16x32_bf16(afl[i], wfh[j], acc[i][j], 0, 0, 0);
        acc[i][j] = __builtin_amdgcn_mfma_f32_16x16x32_bf16(afh[i], wfl[j], acc[i][j], 0, 0, 0);
      }
    __syncthreads();
  }

  // epilogue: C/D layout col=lane&15, row=quad*4+reg; gelu + ssm recon + gate blend
#pragma unroll
  for (int i = 0; i < 4; ++i) {
    const int grow0 = bm * 128 + wm + i * 16 + quad * 4;
    float cd_r[4];
    int hb_r[4];
#pragma unroll
    for (int r = 0; r < 4; ++r) {
      const int gr = grow0 + r;
      const int b = gr >> 11;           // gr = b*2048 + s
      const int c = (gr & 2047) >> 7;   // 128-step chunk
      cd_r[r] = cumd[gr];
      hb_r[r] = (b * 16 + c) << 10;
    }
#pragma unroll
    for (int j = 0; j < 4; ++j) {
      const int gcol = bn * 128 + wn + j * 16 + fm;
      const float Ae = Avec[gcol];
      const float bb = bias[gcol];
#pragma unroll
      for (int r = 0; r < 4; ++r) {
        const int gr = grow0 + r;
        const size_t off = (size_t)gr * 1024 + gcol;
        const float hin = chH[hb_r[r] + gcol];
        const float lcl = C[off];
        const float gt  = gate[off];
        float v = acc[i][j][r] + bb;
        v = 0.5f * v * (1.f + erff(v * 0.70710678118654752f));   // exact gelu
        const float p = __expf(Ae * cd_r[r]);                    // prod of A_bar over chunk prefix
        const float sst = lcl + p * hin;                         // true ssm state
        C[off] = v * gt + sst * (1.f - gt);
      }
    }
  }
}

// ---------------- fused scan + gate + ssm_partial + cumd kernel ----------------
// WGs 0..127: reservoir scan (round-9 structure) with XCD-LOCAL group mapping:
//   go = wg & 7 (batch group), mem = wg >> 3. With round-robin block->XCD dispatch, all 16
//   members of group go land on XCD go, so the group's 4KB hbuf slice stays in that XCD's
//   private L2 -> store->load visibility drops from LLC round-trip to local-L2 latency.
//   CORRECTNESS DOES NOT DEPEND ON PLACEMENT (AGENT-scope atomics are device-coherent;
//   wrong placement only loses the speedup). Guide §6 G16 respected.
// WGs 128..1151: gate = sigmoid(x @ gate_w^T + gate_b) tiles (proven, from round 10).
// WGs 1152..1407: ssm_partial (per-chunk local scan; depends only on prefix outputs).
// WG  1408:       cumd (within-chunk cumulative delta; prefix-only inputs).
// Deadlock-safety: only scan WGs spin, and only on other scan WGs; scan WGs are first in
// dispatch order so all 128 are resident before any spin. Other populations have finite work.
// Scan safety invariants unchanged from round 9.
__global__ __launch_bounds__(512, 2) void scan_gate_kernel(
    float* __restrict__ xin_res,       // [8][2048][1024]: in xin, out res states (in-place)
    const float* __restrict__ Wres,    // [1024][1024]
    unsigned* __restrict__ hbuf,       // [2][8][1024] packed words, zeroed before launch
    const float* __restrict__ x,       // input x [M,1024]
    const float* __restrict__ gate_w,  // [1024,1024]
    const float* __restrict__ gate_b,  // [1024]
    float* __restrict__ gateout,       // [M,1024]
    const float* __restrict__ delta,   // [M]
    const float* __restrict__ Avec,    // [H]
    float* __restrict__ bx,            // d_out: in Bx, out ssm local states (in-place)
    float* __restrict__ chP,           // [B,16,1024] chunk products
    float* __restrict__ cumd)          // [M]
{
  __shared__ __align__(16) unsigned char smem[20480];   // scan: 8KB hs dbuf / gate: 20KB As|Ws
  const int wg  = blockIdx.x;
  const int tid = threadIdx.x;

  if (wg < 128) {
    // ================= scan path (round-9 logic, XCD-local group mapping) =================
    float* hsb = (float*)smem;           // [2][1024]
    const int go  = wg & 7;              // batch group 0..7  == XCD (round-robin assumption)
    const int mem = wg >> 3;             // member: rows mem*64..mem*64+63
    const int g   = tid >> 6;            // wave 0..7
    const int l   = tid & 63;
    const int row8 = mem * 64 + g * 8;   // wave's 8-row base

    // W registers: 8 rows x 16 k per thread (k = 16l .. 16l+15)
    float4 w4[8][4];
#pragma unroll
    for (int r = 0; r < 8; ++r) {
      const float* wrow = Wres + (size_t)(row8 + r) * 1024 + l * 16;
#pragma unroll
      for (int j = 0; j < 4; ++j) w4[r][j] = *(const float4*)(wrow + 4 * j);
    }

    const int m0 = l & 1, m1 = (l >> 1) & 1, m2 = (l >> 2) & 1;
    const int myrow = row8 + (l & 7);    // row this lane finalizes (lanes 8+ duplicate)
    float hprev = 0.f;
    const unsigned long long tmask = 0x0000FFFF0000FFFFull;

    // staging: thread writes floats (2*tid, 2*tid+1) -> logical line Lw=tid>>1, swizzled
    const int Pw = (tid >> 1) ^ ((tid >> 6) & 7);
    const int wofs = Pw * 4 + (tid & 1) * 2;

    for (int s = 0; s < S_; ++s) {
      // prefetch u before the poll (keep-alive pins issue order)
      const float u = xin_res[((size_t)go * S_ + s) * H_ + myrow];
      asm volatile("" :: "v"(u));

      // poll h^s: ONE u64 per thread (rows 2*tid, 2*tid+1 of this group)
      const unsigned tag = (unsigned)s & 0xFFFFu;
      const unsigned long long tag2 = (unsigned long long)tag | ((unsigned long long)tag << 32);
      const unsigned long long* hp =
          (const unsigned long long*)(hbuf + (size_t)(s & 1) * 8192 + go * 1024) + tid;
      unsigned long long w;
      for (;;) {
        w = __hip_atomic_load(hp, __ATOMIC_RELAXED, __HIP_MEMORY_SCOPE_AGENT);
        if (((w ^ tag2) & tmask) == 0ull) break;
      }

      // stage as fp32 (mask off tag), one ds_write_b64 to swizzled line
      float2 hf;
      hf.x = __uint_as_float((unsigned)w & 0xFFFF0000u);
      hf.y = __uint_as_float((unsigned)(w >> 32) & 0xFFFF0000u);
      *(float2*)(hsb + (s & 1) * 1024 + wofs) = hf;
      __syncthreads();                   // the only barrier: staged; all polls done before
                                         // any tag-s+1 store below (safety inv.)

      // matvec: 8 rows x 16 k per thread; 4 wide ds_read_b128 (distinct line/lane)
      const float* hbse = hsb + (s & 1) * 1024;
      float acc0 = 0.f, acc1 = 0.f, acc2 = 0.f, acc3 = 0.f;
      float acc4 = 0.f, acc5 = 0.f, acc6 = 0.f, acc7 = 0.f;
#pragma unroll
      for (int j = 0; j < 4; ++j) {
        const int P = (4 * l + j) ^ ((l >> 3) & 7);
        const float4 h4 = *(const float4*)(hbse + P * 4);
        acc0 += w4[0][j].x * h4.x + w4[0][j].y * h4.y + w4[0][j].z * h4.z + w4[0][j].w * h4.w;
        acc1 += w4[1][j].x * h4.x + w4[1][j].y * h4.y + w4[1][j].z * h4.z + w4[1][j].w * h4.w;
        acc2 += w4[2][j].x * h4.x + w4[2][j].y * h4.y + w4[2][j].z * h4.z + w4[2][j].w * h4.w;
        acc3 += w4[3][j].x * h4.x + w4[3][j].y * h4.y + w4[3][j].z * h4.z + w4[3][j].w * h4.w;
        acc4 += w4[4][j].x * h4.x + w4[4][j].y * h4.y + w4[4][j].z * h4.z + w4[4][j].w * h4.w;
        acc5 += w4[5][j].x * h4.x + w4[5][j].y * h4.y + w4[5][j].z * h4.z + w4[5][j].w * h4.w;
        acc6 += w4[6][j].x * h4.x + w4[6][j].y * h4.y + w4[6][j].z * h4.z + w4[6][j].w * h4.w;
        acc7 += w4[7][j].x * h4.x + w4[7][j].y * h4.y + w4[7][j].z * h4.z + w4[7][j].w * h4.w;
      }

      // butterfly reduce-scatter: rows onto lane bits 0..2, then tree over bits 3..5
      float v0 = (m0 ? acc1 : acc0) + __shfl_xor(m0 ? acc0 : acc1, 1);
      float v1 = (m0 ? acc3 : acc2) + __shfl_xor(m0 ? acc2 : acc3, 1);
      float v2 = (m0 ? acc5 : acc4) + __shfl_xor(m0 ? acc4 : acc5, 1);
      float v3 = (m0 ? acc7 : acc6) + __shfl_xor(m0 ? acc6 : acc7, 1);
      float u0 = (m1 ? v1 : v0) + __shfl_xor(m1 ? v0 : v1, 2);
      float u1 = (m1 ? v3 : v2) + __shfl_xor(m1 ? v2 : v3, 2);
      float ps = (m2 ? u1 : u0) + __shfl_xor(m2 ? u0 : u1, 4);
      ps += __shfl_xor(ps, 8);
      ps += __shfl_xor(ps, 16);
      ps += __shfl_xor(ps, 32);

      // tanh, leak (all lanes; duplicates consistent), lanes 0..7 store
      const float z  = u + ps;
      const float e  = __expf(2.f * z);                 // tanh(z) = 1 - 2/(e^{2z}+1)
      const float hn = 1.f - __fdividef(2.f, e + 1.f);  // saturates correctly
      const float hv = 0.95f * hn + 0.05f * hprev;
      hprev = hv;

      if (l < 8) {
        const unsigned word = ((__float_as_uint(hv) + 0x8000u) & 0xFFFF0000u)
                            | ((unsigned)(s + 1) & 0xFFFFu);
        __hip_atomic_store(hbuf + (size_t)((s + 1) & 1) * 8192 + go * 1024 + myrow, word,
                           __ATOMIC_RELAXED, __HIP_MEMORY_SCOPE_AGENT);
        xin_res[((size_t)go * S_ + s) * H_ + myrow] = hv;  // fp32 states, 32B-dense per wave
      }
      // no drain, no flag, no rendezvous — next iteration's poll is the wait
    }
  } else if (wg < 1152) {
    // ================= gate path: sigmoid(x @ gate_w^T + gate_b) tile =================
    unsigned short* As = (unsigned short*)smem;            // [128*40]
    unsigned short* Ws = As + 128 * 40;                    // [128*40]
    const int bidx = wg - 128;           // 0..1023
    const int bn   = bidx & 7;
    const int bm   = bidx >> 3;
    const bool act = tid < 256;
    const int wave = tid >> 6, lane = tid & 63;            // waves 0..3 active
    const int wm = (wave >> 1) * 64, wn = (wave & 1) * 64;
    const int fm = lane & 15, quad = lane >> 4;

    floatx4 acc[4][4];
#pragma unroll
    for (int i = 0; i < 4; ++i)
#pragma unroll
      for (int j = 0; j < 4; ++j) acc[i][j] = (floatx4){0.f, 0.f, 0.f, 0.f};

    const float* Abase = x + (size_t)bm * 128 * 1024;
    const float* Wbase = gate_w + (size_t)bn * 128 * 1024;

    for (int k0 = 0; k0 < 1024; k0 += 32) {
      if (act) {
        float4 a4[4], w4g[4];
#pragma unroll
        for (int i = 0; i < 4; ++i) {
          const int q = tid + 256 * i;
          const int row = q >> 3, ch = q & 7;
          a4[i]  = *(const float4*)(Abase + (size_t)row * 1024 + k0 + ch * 4);
          w4g[i] = *(const float4*)(Wbase + (size_t)row * 1024 + k0 + ch * 4);
        }
#pragma unroll
        for (int i = 0; i < 4; ++i) {
          const int q = tid + 256 * i;
          const int row = q >> 3, ch = q & 7;
          uint2 pa, pw;
          pa.x = pack_bf16(a4[i].x, a4[i].y);  pa.y = pack_bf16(a4[i].z, a4[i].w);
          pw.x = pack_bf16(w4g[i].x, w4g[i].y); pw.y = pack_bf16(w4g[i].z, w4g[i].w);
          *(uint2*)(&As[row * 40 + ch * 4]) = pa;
          *(uint2*)(&Ws[row * 40 + ch * 4]) = pw;
        }
      }
      __syncthreads();
      if (act) {
        short8 af[4], wf[4];
#pragma unroll
        for (int i = 0; i < 4; ++i) {
          af[i] = *(const short8*)(&As[(wm + i * 16 + fm) * 40 + quad * 8]);
          wf[i] = *(const short8*)(&Ws[(wn + i * 16 + fm) * 40 + quad * 8]);
        }
#pragma unroll
        for (int i = 0; i < 4; ++i)
#pragma unroll
          for (int j = 0; j < 4; ++j)
            acc[i][j] = __builtin_amdgcn_mfma_f32_16x16x32_bf16(af[i], wf[j], acc[i][j], 0, 0, 0);
      }
      __syncthreads();
    }

    if (act) {
      // epilogue: C/D layout col=lane&15, row=quad*4+reg; sigmoid
#pragma unroll
      for (int i = 0; i < 4; ++i) {
        const int grow0 = bm * 128 + wm + i * 16 + quad * 4;
#pragma unroll
        for (int j = 0; j < 4; ++j) {
          const int gcol = bn * 128 + wn + j * 16 + fm;
          const float bb = gate_b[gcol];
#pragma unroll
          for (int r = 0; r < 4; ++r) {
            float v = acc[i][j][r] + bb;
            v = 1.f / (1.f + __expf(-v));
            gateout[(size_t)(grow0 + r) * 1024 + gcol] = v;
          }
        }
      }
    }
  } else if (wg < 1408) {
    // ================= ssm_partial: per-chunk local scan (prefix-only inputs) =================
    const int idx = (wg - 1152) * 512 + tid;   // 0..131071
    const int h = idx & 1023;
    const int c = (idx >> 10) & 15;
    const int b = idx >> 14;
    const float Ah = Avec[h];
    const float inv = 1.f / (Ah + 1e-8f);
    const float* dp = delta + b * S_ + c * 128;
    float* xp = bx + ((size_t)(b * S_ + c * 128)) * H_ + h;
    float p = 1.f, hl = 0.f;
    for (int t = 0; t < 128; ++t) {
      const float a = __expf(Ah * dp[t]);
      const float bb2 = xp[(size_t)t * H_] * (1.f - a) * inv;
      hl = a * hl + bb2;
      p *= a;
      xp[(size_t)t * H_] = hl;
    }
    chP[(b * 16 + c) * 1024 + h] = p;
  } else {
    // ================= cumd: within-chunk cumulative delta (tiny) =================
    if (tid < 128) {
      const int b = tid >> 4, c = tid & 15;
      const int base = b * S_ + c * 128;
      float acc = 0.f;
      for (int i = 0; i < 128; ++i) { acc += delta[base + i]; cumd[base + i] = acc; }
    }
  }
}

// phase B: sequential combine over 16 chunks -> per-chunk initial states
__global__ __launch_bounds__(256) void ssm_combine_kernel(
    const float* __restrict__ P, const float* __restrict__ local, float* __restrict__ Hin)
{
  const int idx = blockIdx.x * 256 + threadIdx.x;  // 8192
  const int h = idx & 1023;
  const int b = idx >> 10;
  float hh = 0.f;
#pragma unroll
  for (int c = 0; c < 16; ++c) {
    const int o = (b * 16 + c) * 1024 + h;
    Hin[o] = hh;
    hh = P[o] * hh + local[((size_t)(b * S_ + c * 128 + 127)) * H_ + h];
  }
}

// ---------------- host launch ----------------
extern "C" void kernel_launch(void* const* d_in, const int* in_sizes, int n_in,
                              void* d_out, int out_size, void* d_ws, size_t ws_size,
                              hipStream_t stream) {
  (void)in_sizes; (void)n_in; (void)out_size; (void)ws_size;
  const float* x      = (const float*)d_in[0];
  const float* W_in   = (const float*)d_in[1];
  const float* W_res  = (const float*)d_in[2];
  const float* norm_g = (const float*)d_in[3];
  const float* norm_b = (const float*)d_in[4];
  const float* dw     = (const float*)d_in[5];
  const float* db     = (const float*)d_in[6];
  const float* Avec   = (const float*)d_in[7];
  const float* B_w    = (const float*)d_in[8];
  const float* ro_g   = (const float*)d_in[9];
  const float* ro_b   = (const float*)d_in[10];
  const float* ro_w   = (const float*)d_in[11];
  const float* ro_bias= (const float*)d_in[12];
  const float* gate_w = (const float*)d_in[13];
  const float* gate_b = (const float*)d_in[14];
  float* out = (float*)d_out;
  float* ws  = (float*)d_ws;

  float*    buf0   = ws;                    // bf16 x_norm (first 32MB), later fp32 gate (64MB)
  float*    buf1   = ws + 16777216;         // xin -> reservoir states (in-place)
  float*    delta  = ws + 33554432;         // [M]
  float*    cumd   = ws + 33570816;         // [M]
  unsigned* hbuf   = (unsigned*)(ws + 33587200);  // [2][8][1024] packed words
  float2*   stats  = (float2*)(ws + 33603712);
  float*    chP    = ws + 33636480;         // [B,16,1024]
  float*    chH    = ws + 33767552;         // [B,16,1024]
  unsigned short* xnb = (unsigned short*)buf0;            // bf16 x_norm [M,1024]
  unsigned short* wib = (unsigned short*)(ws + 33898624); // bf16 W_in   [1024,1024]
  unsigned short* bwb = (unsigned short*)(ws + 34422912); // bf16 B_w
  unsigned short* roh = (unsigned short*)(ws + 34947200); // bf16 hi(ro_w)
  unsigned short* rol = (unsigned short*)(ws + 35471488); // bf16 lo(ro_w)

  // 0. weight conversions (once per launch, tiny)
  tobf16_kernel<<<1024, 256, 0, stream>>>(W_in, wib);
  tobf16_kernel<<<1024, 256, 0, stream>>>(B_w, bwb);
  splitw_kernel<<<1024, 256, 0, stream>>>(ro_w, roh, rol);
  // 1. layernorm -> bf16 x_norm + delta
  ln_delta_kernel<<<M_, 256, 0, stream>>>(x, norm_g, norm_b, dw, db, xnb, delta);
  // 2. xin = x_norm @ W_in^T   -> buf1   (bf16 x bf16 MFMA)
  gemm_bb<<<1024, 256, 0, stream>>>(xnb, wib, buf1);
  // 3. Bx = x_norm @ B_w^T     -> d_out (scratch)
  gemm_bb<<<1024, 256, 0, stream>>>(xnb, bwb, out);
  // 4. fused: scan (WGs 0..127, XCD-local groups) + gate (128..1151, -> buf0; xnb dead)
  //          + ssm_partial (1152..1407) + cumd (1408)
  hipMemsetAsync(hbuf, 0, 2 * 8192 * sizeof(unsigned), stream);
  scan_gate_kernel<<<1409, 512, 0, stream>>>(buf1, W_res, hbuf, x, gate_w, gate_b, buf0,
                                             delta, Avec, out, chP, cumd);
  // 5. ssm combine (needs chP + local states from the fused kernel)
  ssm_combine_kernel<<<32, 256, 0, stream>>>(chP, out, chH);
  // 6. ro-layernorm stats
  rowstats_kernel<<<M_, 256, 0, stream>>>(buf1, stats);
  // 7. readout GEMM (MFMA hi/lo, pre-split W) + gelu + ssm recon + gate blend -> d_out
  gemm_readout_mfma<<<1024, 256, 0, stream>>>(buf1, roh, rol, ro_bias, stats, ro_g, ro_b,
                                              Avec, cumd, chH, buf0, out);
}